// Round 1
// baseline (982.580 us; speedup 1.0000x reference)
//
#include <hip/hip_runtime.h>
#include <cstdint>
#include <cstddef>

#define B_   2
#define S_   2048
#define D_   4096
#define H_   32
#define KVH_ 8
#define HD_  128

typedef unsigned short u16;
typedef short     bf16x8 __attribute__((ext_vector_type(8)));
typedef float     f32x4  __attribute__((ext_vector_type(4)));
typedef u16       u16x8  __attribute__((ext_vector_type(8)));

__device__ __forceinline__ u16 f2bf(float f) {
  union { float f; uint32_t u; } v; v.f = f;
  uint32_t u = v.u;
  return (u16)((u + 0x7fffu + ((u >> 16) & 1u)) >> 16);
}
__device__ __forceinline__ float bf2f(u16 h) {
  union { uint32_t u; float f; } v; v.u = ((uint32_t)h) << 16;
  return v.f;
}

// async global->LDS, 16B per lane, wave-uniform LDS base
__device__ __forceinline__ void gl_lds16(const void* g, void* l) {
  __builtin_amdgcn_global_load_lds(
      (const __attribute__((address_space(1))) void*)g,
      (__attribute__((address_space(3))) void*)l, 16, 0, 0);
}

#define MFMA(a, b, c) __builtin_amdgcn_mfma_f32_16x16x32_bf16((a), (b), (c), 0, 0, 0)

// ---------------- cast f32 -> bf16 (8 elems / thread) ----------------
__global__ void cast_kernel(const float* __restrict__ in, u16* __restrict__ out, int n8) {
  int i = blockIdx.x * blockDim.x + threadIdx.x;
  if (i >= n8) return;
  const float4* p = (const float4*)in + (size_t)i * 2;
  float4 a = p[0], b = p[1];
  u16x8 r;
  r[0] = f2bf(a.x); r[1] = f2bf(a.y); r[2] = f2bf(a.z); r[3] = f2bf(a.w);
  r[4] = f2bf(b.x); r[5] = f2bf(b.y); r[6] = f2bf(b.z); r[7] = f2bf(b.w);
  *((u16x8*)out + i) = r;
}

// ---------------- GEMM-NT: C[M][N] = A[M][K] * B[N][K]^T (bf16 in) ----------------
// 128x128 tile, BK=32, 4 waves (2x2), 16x16x32 MFMA, global_load_lds staging.
template <bool OUT_F32>
__global__ __launch_bounds__(256, 2)
void gemm_bt(const u16* __restrict__ A, const u16* __restrict__ Bw,
             void* __restrict__ C, int M, int N, int K) {
  __shared__ u16 lA[128 * 32];
  __shared__ u16 lB[128 * 32];
  const int tid = threadIdx.x;
  const int w = tid >> 6, l = tid & 63;
  const int lc = l & 15, lg = l >> 4;
  const int bn = blockIdx.x, bm = blockIdx.y;
  const int wr = w >> 1, wc = w & 1;
  const u16* Ab = A + (size_t)(bm * 128) * K;
  const u16* Bb = Bw + (size_t)(bn * 128) * K;
  const int srow = l >> 2;         // 0..15 rows per wave-load
  const int scol = (l & 3) * 8;    // 8-elem (16B) column chunk

  f32x4 acc[4][4];
#pragma unroll
  for (int i = 0; i < 4; ++i)
#pragma unroll
    for (int j = 0; j < 4; ++j) acc[i][j] = (f32x4){0.f, 0.f, 0.f, 0.f};

  const int nk = K >> 5;
  for (int kt = 0; kt < nk; ++kt) {
    const int k0 = kt * 32;
    __syncthreads();
#pragma unroll
    for (int i = 0; i < 2; ++i) {
      const int rowA = (w * 2 + i) * 16;  // wave-uniform
      gl_lds16(Ab + (size_t)(rowA + srow) * K + k0 + scol, &lA[rowA * 32]);
      gl_lds16(Bb + (size_t)(rowA + srow) * K + k0 + scol, &lB[rowA * 32]);
    }
    __syncthreads();
    bf16x8 af[4], bfr[4];
#pragma unroll
    for (int mi = 0; mi < 4; ++mi)
      af[mi] = *(const bf16x8*)&lA[(wr * 64 + mi * 16 + lc) * 32 + lg * 8];
#pragma unroll
    for (int ni = 0; ni < 4; ++ni)
      bfr[ni] = *(const bf16x8*)&lB[(wc * 64 + ni * 16 + lc) * 32 + lg * 8];
#pragma unroll
    for (int mi = 0; mi < 4; ++mi)
#pragma unroll
      for (int ni = 0; ni < 4; ++ni)
        acc[mi][ni] = MFMA(af[mi], bfr[ni], acc[mi][ni]);
  }

#pragma unroll
  for (int mi = 0; mi < 4; ++mi)
#pragma unroll
    for (int ni = 0; ni < 4; ++ni)
#pragma unroll
      for (int r = 0; r < 4; ++r) {
        const int row = bm * 128 + wr * 64 + mi * 16 + lg * 4 + r;
        const int col = bn * 128 + wc * 64 + ni * 16 + lc;
        if constexpr (OUT_F32)
          ((float*)C)[(size_t)row * N + col] = acc[mi][ni][r];
        else
          ((u16*)C)[(size_t)row * N + col] = f2bf(acc[mi][ni][r]);
      }
}

// ---------------- RoPE: [t][h*128+d] bf16 -> [b][h][s][d] bf16 ----------------
template <int NH>
__global__ void rope_kernel(const u16* __restrict__ lin, const float* __restrict__ fr,
                            u16* __restrict__ out) {
  int idx = blockIdx.x * 256 + threadIdx.x;
  const int total = B_ * S_ * NH * 64;
  if (idx >= total) return;
  const int i = idx & 63;
  const int h = (idx >> 6) % NH;
  const int t = idx / (64 * NH);
  const int s = t & (S_ - 1);
  const int b = t >> 11;
  const size_t src = (size_t)t * (NH * HD_) + h * HD_ + 2 * i;
  const float x0 = bf2f(lin[src]);
  const float x1 = bf2f(lin[src + 1]);
  const float2 cs = ((const float2*)fr)[s * 64 + i];
  const float o0 = x0 * cs.x - x1 * cs.y;
  const float o1 = x1 * cs.x + x0 * cs.y;
  const size_t dst = ((size_t)((b * NH + h) * S_ + s)) * HD_ + 2 * i;
  out[dst] = f2bf(o0);
  out[dst + 1] = f2bf(o1);
}

// ---------------- V transpose: [t][kv*128+d] -> [b][kv][d][s] ----------------
__global__ void vtrans_kernel(const u16* __restrict__ vlin, u16* __restrict__ vt) {
  __shared__ u16 tile[32][33];
  const int tx = threadIdx.x, ty = threadIdx.y;  // (32, 8)
  const int s0 = blockIdx.x * 32;
  const int d0 = blockIdx.y * 32;
  const int bk = blockIdx.z;  // b*KVH + kv
  const int b = bk >> 3, kv = bk & 7;
#pragma unroll
  for (int r = 0; r < 4; ++r) {
    const int s = s0 + ty + r * 8;
    tile[ty + r * 8][tx] = vlin[((size_t)(b * S_ + s)) * (KVH_ * HD_) + kv * HD_ + d0 + tx];
  }
  __syncthreads();
#pragma unroll
  for (int r = 0; r < 4; ++r) {
    const int d = d0 + ty + r * 8;
    vt[((size_t)bk * HD_ + d) * S_ + s0 + tx] = tile[tx][ty + r * 8];
  }
}

// ---------------- causal GQA flash attention ----------------
// Q: [B][H][S][128], K: [B][KVH][S][128], Vt: [B][KVH][128][S], O: [B][S][H*128]
// 4 independent waves/block, 32 q-rows/wave, 32-key tiles.
__global__ __launch_bounds__(256, 2)
void attn_kernel(const u16* __restrict__ Q, const u16* __restrict__ K,
                 const u16* __restrict__ V, u16* __restrict__ O) {
  __shared__ u16 Plds[4][32 * 32];
  const int tid = threadIdx.x;
  const int w = tid >> 6, l = tid & 63;
  const int lc = l & 15, lg = l >> 4;
  const int qb = blockIdx.x * 128;
  const int h = blockIdx.y, b = blockIdx.z;
  const int kv = h >> 2;
  const int qw = qb + w * 32;
  const u16* Qp = Q + ((size_t)(b * H_ + h) * S_ + qw) * HD_;
  const u16* Kp = K + ((size_t)(b * KVH_ + kv) * S_) * HD_;
  const u16* Vp = V + ((size_t)(b * KVH_ + kv) * HD_) * S_;
  u16* myP = &Plds[w][0];

  // Q fragments held in registers for the whole k-loop
  bf16x8 qf[2][4];
#pragma unroll
  for (int mf = 0; mf < 2; ++mf)
#pragma unroll
    for (int kd = 0; kd < 4; ++kd)
      qf[mf][kd] = *(const bf16x8*)(Qp + (size_t)(mf * 16 + lc) * HD_ + kd * 32 + lg * 8);

  f32x4 out[2][8];
#pragma unroll
  for (int mf = 0; mf < 2; ++mf)
#pragma unroll
    for (int n = 0; n < 8; ++n) out[mf][n] = (f32x4){0.f, 0.f, 0.f, 0.f};
  float mrun[2][4], lrun[2][4];
#pragma unroll
  for (int mf = 0; mf < 2; ++mf)
#pragma unroll
    for (int r = 0; r < 4; ++r) { mrun[mf][r] = -1e30f; lrun[mf][r] = 0.f; }

  const int nt = (qw >> 5) + 1;  // causal extent for this wave
  for (int t = 0; t < nt; ++t) {
    const int k0 = t * 32;
    // ---- scores = Q K^T
    f32x4 sc[2][2];
#pragma unroll
    for (int mf = 0; mf < 2; ++mf)
#pragma unroll
      for (int nf = 0; nf < 2; ++nf) sc[mf][nf] = (f32x4){0.f, 0.f, 0.f, 0.f};
#pragma unroll
    for (int nf = 0; nf < 2; ++nf)
#pragma unroll
      for (int kd = 0; kd < 4; ++kd) {
        bf16x8 kf = *(const bf16x8*)(Kp + (size_t)(k0 + nf * 16 + lc) * HD_ + kd * 32 + lg * 8);
        sc[0][nf] = MFMA(qf[0][kd], kf, sc[0][nf]);
        sc[1][nf] = MFMA(qf[1][kd], kf, sc[1][nf]);
      }
    const float scl = 0.08838834764831845f;  // 1/sqrt(128)
    const bool diag = (t == nt - 1);
    float p[2][2][4];
#pragma unroll
    for (int mf = 0; mf < 2; ++mf)
#pragma unroll
      for (int nf = 0; nf < 2; ++nf)
#pragma unroll
        for (int r = 0; r < 4; ++r) {
          float v = sc[mf][nf][r] * scl;
          if (diag && (k0 + nf * 16 + lc > qw + mf * 16 + lg * 4 + r)) v = -1e9f;
          p[mf][nf][r] = v;
        }
    // ---- online softmax (fp32)
#pragma unroll
    for (int mf = 0; mf < 2; ++mf)
#pragma unroll
      for (int r = 0; r < 4; ++r) {
        float rm = fmaxf(p[mf][0][r], p[mf][1][r]);
        rm = fmaxf(rm, __shfl_xor(rm, 1, 16));
        rm = fmaxf(rm, __shfl_xor(rm, 2, 16));
        rm = fmaxf(rm, __shfl_xor(rm, 4, 16));
        rm = fmaxf(rm, __shfl_xor(rm, 8, 16));
        const float mnew = fmaxf(mrun[mf][r], rm);
        const float alpha = __expf(mrun[mf][r] - mnew);
        mrun[mf][r] = mnew;
        lrun[mf][r] *= alpha;
#pragma unroll
        for (int n = 0; n < 8; ++n) out[mf][n][r] *= alpha;
      }
#pragma unroll
    for (int mf = 0; mf < 2; ++mf)
#pragma unroll
      for (int r = 0; r < 4; ++r) {
        const float e0 = __expf(p[mf][0][r] - mrun[mf][r]);
        const float e1 = __expf(p[mf][1][r] - mrun[mf][r]);
        p[mf][0][r] = e0;
        p[mf][1][r] = e1;
        float sum = e0 + e1;
        sum += __shfl_xor(sum, 1, 16);
        sum += __shfl_xor(sum, 2, 16);
        sum += __shfl_xor(sum, 4, 16);
        sum += __shfl_xor(sum, 8, 16);
        lrun[mf][r] += sum;
      }
    // ---- P -> LDS (D-layout) then re-read in A-layout
#pragma unroll
    for (int mf = 0; mf < 2; ++mf)
#pragma unroll
      for (int nf = 0; nf < 2; ++nf)
#pragma unroll
        for (int r = 0; r < 4; ++r)
          myP[(mf * 16 + lg * 4 + r) * 32 + nf * 16 + lc] = f2bf(p[mf][nf][r]);
    asm volatile("s_waitcnt lgkmcnt(0)" ::: "memory");
    bf16x8 pf[2];
    pf[0] = *(const bf16x8*)&myP[lc * 32 + lg * 8];
    pf[1] = *(const bf16x8*)&myP[(16 + lc) * 32 + lg * 8];
    // ---- out += P V  (V read transposed: contiguous along s)
#pragma unroll
    for (int n = 0; n < 8; ++n) {
      bf16x8 vf = *(const bf16x8*)(Vp + (size_t)(n * 16 + lc) * S_ + k0 + lg * 8);
      out[0][n] = MFMA(pf[0], vf, out[0][n]);
      out[1][n] = MFMA(pf[1], vf, out[1][n]);
    }
  }
  // ---- epilogue: normalize, store [b][s][h*128+d] bf16
#pragma unroll
  for (int mf = 0; mf < 2; ++mf)
#pragma unroll
    for (int r = 0; r < 4; ++r) {
      const int s = qw + mf * 16 + lg * 4 + r;
      const float inv = 1.0f / lrun[mf][r];
      const size_t base = ((size_t)(b * S_ + s)) * (H_ * HD_) + h * HD_;
#pragma unroll
      for (int n = 0; n < 8; ++n)
        O[base + n * 16 + lc] = f2bf(out[mf][n][r] * inv);
    }
}

// ---------------- launch ----------------
extern "C" void kernel_launch(void* const* d_in, const int* in_sizes, int n_in,
                              void* d_out, int out_size, void* d_ws, size_t ws_size,
                              hipStream_t stream) {
  const float* x     = (const float*)d_in[0];
  const float* freqs = (const float*)d_in[2];
  const float* wq    = (const float*)d_in[4];
  const float* wk    = (const float*)d_in[5];
  const float* wv    = (const float*)d_in[6];
  const float* wo    = (const float*)d_in[7];

  char* ws = (char*)d_ws;
  u16* xb   = (u16*)(ws + 0);          // 33,554,432 B
  u16* wqb  = (u16*)(ws + 33554432);   // 33,554,432 B
  u16* wkb  = (u16*)(ws + 67108864);   // 8,388,608 B
  u16* wvb  = (u16*)(ws + 75497472);   // 8,388,608 B
  u16* qlin = (u16*)(ws + 83886080);   // 33,554,432 B
  u16* klin = (u16*)(ws + 117440512);  // 8,388,608 B
  u16* vlin = (u16*)(ws + 125829120);  // 8,388,608 B  (end = 128 MiB)
  // reuse after producers are done:
  u16* qr   = wqb;   // rope'd Q  [B][H][S][128]
  u16* kr   = wkb;   // rope'd K  [B][KVH][S][128]
  u16* vt   = wvb;   // V^T       [B][KVH][128][S]
  u16* aout = qlin;  // attention output [t][h*128+d]
  u16* wob  = xb;    // bf16 wo

  // casts
  cast_kernel<<<8192, 256, 0, stream>>>(x, xb, 2097152);
  cast_kernel<<<8192, 256, 0, stream>>>(wq, wqb, 2097152);
  cast_kernel<<<2048, 256, 0, stream>>>(wk, wkb, 524288);
  cast_kernel<<<2048, 256, 0, stream>>>(wv, wvb, 524288);
  // projections
  gemm_bt<false><<<dim3(32, 32), 256, 0, stream>>>(xb, wqb, qlin, 4096, 4096, 4096);
  gemm_bt<false><<<dim3(8, 32), 256, 0, stream>>>(xb, wkb, klin, 4096, 1024, 4096);
  gemm_bt<false><<<dim3(8, 32), 256, 0, stream>>>(xb, wvb, vlin, 4096, 1024, 4096);
  // rope (qlin->qr overwrites wqb, klin->kr overwrites wkb: producers done)
  rope_kernel<32><<<32768, 256, 0, stream>>>(qlin, freqs, qr);
  rope_kernel<8><<<8192, 256, 0, stream>>>(klin, freqs, kr);
  // V transpose (vlin->vt overwrites wvb)
  vtrans_kernel<<<dim3(64, 4, 16), dim3(32, 8), 0, stream>>>(vlin, vt);
  // attention (writes into qlin region)
  attn_kernel<<<dim3(16, 32, 2), 256, 0, stream>>>(qr, kr, vt, aout);
  // wo cast into xb region (x consumed), then output projection (fp32 out)
  cast_kernel<<<8192, 256, 0, stream>>>(wo, wob, 2097152);
  gemm_bt<true><<<dim3(32, 32), 256, 0, stream>>>(aout, wob, d_out, 4096, 4096, 4096);
}

// Round 2
// 798.905 us; speedup vs baseline: 1.2299x; 1.2299x over previous
//
#include <hip/hip_runtime.h>
#include <cstdint>
#include <cstddef>

#define B_   2
#define S_   2048
#define D_   4096
#define H_   32
#define KVH_ 8
#define HD_  128

typedef unsigned short u16;
typedef short     bf16x8 __attribute__((ext_vector_type(8)));
typedef float     f32x4  __attribute__((ext_vector_type(4)));
typedef u16       u16x8  __attribute__((ext_vector_type(8)));

__device__ __forceinline__ u16 f2bf(float f) {
  union { float f; uint32_t u; } v; v.f = f;
  uint32_t u = v.u;
  return (u16)((u + 0x7fffu + ((u >> 16) & 1u)) >> 16);
}
__device__ __forceinline__ float bf2f(u16 h) {
  union { uint32_t u; float f; } v; v.u = ((uint32_t)h) << 16;
  return v.f;
}

// async global->LDS, 16B per lane, wave-uniform LDS base
__device__ __forceinline__ void gl_lds16(const void* g, void* l) {
  __builtin_amdgcn_global_load_lds(
      (const __attribute__((address_space(1))) void*)g,
      (__attribute__((address_space(3))) void*)l, 16, 0, 0);
}

#define MFMA(a, b, c) __builtin_amdgcn_mfma_f32_16x16x32_bf16((a), (b), (c), 0, 0, 0)

// ---------------- cast f32 -> bf16 (8 elems / thread) ----------------
__global__ void cast_kernel(const float* __restrict__ in, u16* __restrict__ out, int n8) {
  int i = blockIdx.x * blockDim.x + threadIdx.x;
  if (i >= n8) return;
  const float4* p = (const float4*)in + (size_t)i * 2;
  float4 a = p[0], b = p[1];
  u16x8 r;
  r[0] = f2bf(a.x); r[1] = f2bf(a.y); r[2] = f2bf(a.z); r[3] = f2bf(a.w);
  r[4] = f2bf(b.x); r[5] = f2bf(b.y); r[6] = f2bf(b.z); r[7] = f2bf(b.w);
  *((u16x8*)out + i) = r;
}

// ---------------- GEMM-NT: C[M][N] = A[M][K] * B[N][K]^T (bf16 in) ----------------
template <bool OUT_F32>
__global__ __launch_bounds__(256, 2)
void gemm_bt(const u16* __restrict__ A, const u16* __restrict__ Bw,
             void* __restrict__ C, int M, int N, int K) {
  __shared__ u16 lA[128 * 32];
  __shared__ u16 lB[128 * 32];
  const int tid = threadIdx.x;
  const int w = tid >> 6, l = tid & 63;
  const int lc = l & 15, lg = l >> 4;
  const int bn = blockIdx.x, bm = blockIdx.y;
  const int wr = w >> 1, wc = w & 1;
  const u16* Ab = A + (size_t)(bm * 128) * K;
  const u16* Bb = Bw + (size_t)(bn * 128) * K;
  const int srow = l >> 2;
  const int scol = (l & 3) * 8;

  f32x4 acc[4][4];
#pragma unroll
  for (int i = 0; i < 4; ++i)
#pragma unroll
    for (int j = 0; j < 4; ++j) acc[i][j] = (f32x4){0.f, 0.f, 0.f, 0.f};

  const int nk = K >> 5;
  for (int kt = 0; kt < nk; ++kt) {
    const int k0 = kt * 32;
    __syncthreads();
#pragma unroll
    for (int i = 0; i < 2; ++i) {
      const int rowA = (w * 2 + i) * 16;
      gl_lds16(Ab + (size_t)(rowA + srow) * K + k0 + scol, &lA[rowA * 32]);
      gl_lds16(Bb + (size_t)(rowA + srow) * K + k0 + scol, &lB[rowA * 32]);
    }
    __syncthreads();
    bf16x8 af[4], bfr[4];
#pragma unroll
    for (int mi = 0; mi < 4; ++mi)
      af[mi] = *(const bf16x8*)&lA[(wr * 64 + mi * 16 + lc) * 32 + lg * 8];
#pragma unroll
    for (int ni = 0; ni < 4; ++ni)
      bfr[ni] = *(const bf16x8*)&lB[(wc * 64 + ni * 16 + lc) * 32 + lg * 8];
#pragma unroll
    for (int mi = 0; mi < 4; ++mi)
#pragma unroll
      for (int ni = 0; ni < 4; ++ni)
        acc[mi][ni] = MFMA(af[mi], bfr[ni], acc[mi][ni]);
  }

#pragma unroll
  for (int mi = 0; mi < 4; ++mi)
#pragma unroll
    for (int ni = 0; ni < 4; ++ni)
#pragma unroll
      for (int r = 0; r < 4; ++r) {
        const int row = bm * 128 + wr * 64 + mi * 16 + lg * 4 + r;
        const int col = bn * 128 + wc * 64 + ni * 16 + lc;
        if constexpr (OUT_F32)
          ((float*)C)[(size_t)row * N + col] = acc[mi][ni][r];
        else
          ((u16*)C)[(size_t)row * N + col] = f2bf(acc[mi][ni][r]);
      }
}

// ---------------- RoPE ----------------
template <int NH>
__global__ void rope_kernel(const u16* __restrict__ lin, const float* __restrict__ fr,
                            u16* __restrict__ out) {
  int idx = blockIdx.x * 256 + threadIdx.x;
  const int total = B_ * S_ * NH * 64;
  if (idx >= total) return;
  const int i = idx & 63;
  const int h = (idx >> 6) % NH;
  const int t = idx / (64 * NH);
  const int s = t & (S_ - 1);
  const int b = t >> 11;
  const size_t src = (size_t)t * (NH * HD_) + h * HD_ + 2 * i;
  const float x0 = bf2f(lin[src]);
  const float x1 = bf2f(lin[src + 1]);
  const float2 cs = ((const float2*)fr)[s * 64 + i];
  const float o0 = x0 * cs.x - x1 * cs.y;
  const float o1 = x1 * cs.x + x0 * cs.y;
  const size_t dst = ((size_t)((b * NH + h) * S_ + s)) * HD_ + 2 * i;
  out[dst] = f2bf(o0);
  out[dst + 1] = f2bf(o1);
}

// ---------------- V transpose: [t][kv*128+d] -> [b][kv][d][s] ----------------
__global__ void vtrans_kernel(const u16* __restrict__ vlin, u16* __restrict__ vt) {
  __shared__ u16 tile[32][33];
  const int tx = threadIdx.x, ty = threadIdx.y;  // (32, 8)
  const int s0 = blockIdx.x * 32;
  const int d0 = blockIdx.y * 32;
  const int bk = blockIdx.z;
  const int b = bk >> 3, kv = bk & 7;
#pragma unroll
  for (int r = 0; r < 4; ++r) {
    const int s = s0 + ty + r * 8;
    tile[ty + r * 8][tx] = vlin[((size_t)(b * S_ + s)) * (KVH_ * HD_) + kv * HD_ + d0 + tx];
  }
  __syncthreads();
#pragma unroll
  for (int r = 0; r < 4; ++r) {
    const int d = d0 + ty + r * 8;
    vt[((size_t)bk * HD_ + d) * S_ + s0 + tx] = tile[tx][ty + r * 8];
  }
}

// ---------------- causal GQA flash attention (LDS-staged, 2-phase pipeline) ----
// Q: [B][H][S][128], K: [B][KVH][S][128], Vt: [B][KVH][128][S], O: [B][S][H*128]
// 4 waves/block, 32 q-rows/wave (128 rows/block, one head), KVBLK=64,
// K/V double-buffered in LDS w/ XOR swizzle, counted vmcnt, raw s_barrier.
__global__ __launch_bounds__(256, 2)
void attn_kernel(const u16* __restrict__ Q, const u16* __restrict__ K,
                 const u16* __restrict__ V, u16* __restrict__ O) {
  __shared__ u16 sK[2][64 * HD_];   // 32 KB: [kv-row][d], chunk-swizzled
  __shared__ u16 sV[2][HD_ * 64];   // 32 KB: [d][kv-col], chunk-swizzled
  __shared__ u16 sP[4][32 * 64];    // 16 KB: per-wave P roundtrip, swizzled
  const int tid = threadIdx.x;
  const int w = tid >> 6, l = tid & 63;
  const int lc = l & 15, lg = l >> 4;
  const int qb = (15 - blockIdx.x) * 128;  // longest blocks first
  const int h = blockIdx.y, b = blockIdx.z;
  const int kv = h >> 2;
  const int qw = qb + w * 32;
  const u16* Qp = Q + ((size_t)(b * H_ + h) * S_ + qw) * HD_;
  const u16* Kp = K + ((size_t)(b * KVH_ + kv) * S_) * HD_;
  const u16* Vp = V + ((size_t)(b * KVH_ + kv) * HD_) * S_;
  u16* myP = &sP[w][0];

  // per-lane staging offsets (source pre-swizzle; LDS dest stays linear)
  int koff[4], voff[4];
#pragma unroll
  for (int i = 0; i < 4; ++i) {
    const int kr = w * 16 + i * 4 + (l >> 4);      // K tile row this lane fills
    koff[i] = kr * HD_ + ((l & 15) ^ (kr & 7)) * 8;
    const int vr = w * 32 + i * 8 + (l >> 3);      // V tile row (d)
    voff[i] = vr * S_ + ((l & 7) ^ (vr & 7)) * 8;
  }
  // swizzled LDS read chunk offsets (chunk = (kd*4+lg) ^ (row&7), row&7 == lc&7)
  int ck[4];
#pragma unroll
  for (int kd = 0; kd < 4; ++kd) ck[kd] = (((kd * 4 + lg) ^ (lc & 7))) * 8;

  // Q fragments in registers for the whole loop
  bf16x8 qf[2][4];
#pragma unroll
  for (int mf = 0; mf < 2; ++mf)
#pragma unroll
    for (int kd = 0; kd < 4; ++kd)
      qf[mf][kd] = *(const bf16x8*)(Qp + (size_t)(mf * 16 + lc) * HD_ + kd * 32 + lg * 8);
  asm volatile("s_waitcnt vmcnt(0)" ::: "memory");  // clean VMEM scoreboard

  f32x4 out[2][8];
#pragma unroll
  for (int mf = 0; mf < 2; ++mf)
#pragma unroll
    for (int n = 0; n < 8; ++n) out[mf][n] = (f32x4){0.f, 0.f, 0.f, 0.f};
  float mrun[2][4], lrun[2][4];
#pragma unroll
  for (int mf = 0; mf < 2; ++mf)
#pragma unroll
    for (int r = 0; r < 4; ++r) { mrun[mf][r] = -1e30f; lrun[mf][r] = 0.f; }

  auto STAGE = [&](int bufi, int ti) {
    const u16* kg = Kp + (size_t)ti * (64 * HD_);
    const u16* vg = Vp + (size_t)ti * 64;
#pragma unroll
    for (int i = 0; i < 4; ++i) {
      gl_lds16(kg + koff[i], &sK[bufi][(w * 16 + i * 4) * HD_]);
      gl_lds16(vg + voff[i], &sV[bufi][(w * 32 + i * 8) * 64]);
    }
  };

  const int nt_w = (qw >> 6) + 1;       // this wave's causal tile extent
  const int nt = (qb >> 6) + 2;         // block's tile count
  const float scl = 0.08838834764831845f;  // 1/sqrt(128)
  int cur = 0;
  STAGE(0, 0);

  for (int t = 0; t < nt; ++t) {
    if (t + 1 < nt) {
      STAGE(cur ^ 1, t + 1);
      asm volatile("s_waitcnt vmcnt(8)" ::: "memory");  // buf[cur]'s 8 loads done
    } else {
      asm volatile("s_waitcnt vmcnt(0)" ::: "memory");
    }
    __builtin_amdgcn_s_barrier();
    asm volatile("" ::: "memory");

    if (t < nt_w) {
      const int k0 = t * 64;
      // ---- scores = Q K^T
      f32x4 sc[2][4];
#pragma unroll
      for (int mf = 0; mf < 2; ++mf)
#pragma unroll
        for (int nf = 0; nf < 4; ++nf) sc[mf][nf] = (f32x4){0.f, 0.f, 0.f, 0.f};
      __builtin_amdgcn_s_setprio(1);
#pragma unroll
      for (int nf = 0; nf < 4; ++nf) {
        const int krow = (nf * 16 + lc) * HD_;
#pragma unroll
        for (int kd = 0; kd < 4; ++kd) {
          bf16x8 kf = *(const bf16x8*)&sK[cur][krow + ck[kd]];
          sc[0][nf] = MFMA(qf[0][kd], kf, sc[0][nf]);
          sc[1][nf] = MFMA(qf[1][kd], kf, sc[1][nf]);
        }
      }
      __builtin_amdgcn_s_setprio(0);
      // ---- scale + causal mask
      const bool diag = (t == nt_w - 1);
      float p[2][4][4];
#pragma unroll
      for (int mf = 0; mf < 2; ++mf)
#pragma unroll
        for (int nf = 0; nf < 4; ++nf)
#pragma unroll
          for (int r = 0; r < 4; ++r) {
            float v = sc[mf][nf][r] * scl;
            if (diag && (k0 + nf * 16 + lc > qw + mf * 16 + lg * 4 + r)) v = -1e9f;
            p[mf][nf][r] = v;
          }
      // ---- online softmax (fp32, reduce over lc via 16-wide shfl)
#pragma unroll
      for (int mf = 0; mf < 2; ++mf)
#pragma unroll
        for (int r = 0; r < 4; ++r) {
          float rm = fmaxf(fmaxf(p[mf][0][r], p[mf][1][r]),
                           fmaxf(p[mf][2][r], p[mf][3][r]));
          rm = fmaxf(rm, __shfl_xor(rm, 1, 16));
          rm = fmaxf(rm, __shfl_xor(rm, 2, 16));
          rm = fmaxf(rm, __shfl_xor(rm, 4, 16));
          rm = fmaxf(rm, __shfl_xor(rm, 8, 16));
          const float mnew = fmaxf(mrun[mf][r], rm);
          const float alpha = __expf(mrun[mf][r] - mnew);
          mrun[mf][r] = mnew;
          lrun[mf][r] *= alpha;
#pragma unroll
          for (int n = 0; n < 8; ++n) out[mf][n][r] *= alpha;
        }
#pragma unroll
      for (int mf = 0; mf < 2; ++mf)
#pragma unroll
        for (int r = 0; r < 4; ++r) {
          float sum = 0.f;
#pragma unroll
          for (int nf = 0; nf < 4; ++nf) {
            const float e = __expf(p[mf][nf][r] - mrun[mf][r]);
            p[mf][nf][r] = e;
            sum += e;
          }
          sum += __shfl_xor(sum, 1, 16);
          sum += __shfl_xor(sum, 2, 16);
          sum += __shfl_xor(sum, 4, 16);
          sum += __shfl_xor(sum, 8, 16);
          lrun[mf][r] += sum;
        }
      // ---- P -> LDS (swizzled) then re-read as A-fragments
#pragma unroll
      for (int mf = 0; mf < 2; ++mf)
#pragma unroll
        for (int nf = 0; nf < 4; ++nf)
#pragma unroll
          for (int r = 0; r < 4; ++r) {
            const int row = mf * 16 + lg * 4 + r;
            const int cch = (nf * 2 + (lc >> 3)) ^ ((lg * 4 + r) & 7);
            myP[row * 64 + cch * 8 + (lc & 7)] = f2bf(p[mf][nf][r]);
          }
      asm volatile("s_waitcnt lgkmcnt(0)" ::: "memory");
      __builtin_amdgcn_sched_barrier(0);
      bf16x8 pf[2][2];
#pragma unroll
      for (int mf = 0; mf < 2; ++mf)
#pragma unroll
        for (int ks = 0; ks < 2; ++ks)
          pf[mf][ks] = *(const bf16x8*)&myP[(mf * 16 + lc) * 64 + ck[ks]];
      // ---- out += P V
      __builtin_amdgcn_s_setprio(1);
#pragma unroll
      for (int n = 0; n < 8; ++n) {
        const int vrow = (n * 16 + lc) * 64;
#pragma unroll
        for (int ks = 0; ks < 2; ++ks) {
          bf16x8 vf = *(const bf16x8*)&sV[cur][vrow + ck[ks]];
          out[0][n] = MFMA(pf[0][ks], vf, out[0][n]);
          out[1][n] = MFMA(pf[1][ks], vf, out[1][n]);
        }
      }
      __builtin_amdgcn_s_setprio(0);
    }
    asm volatile("" ::: "memory");
    __builtin_amdgcn_s_barrier();
    cur ^= 1;
  }

  // ---- epilogue: normalize, store [b][s][h*128+d] bf16
#pragma unroll
  for (int mf = 0; mf < 2; ++mf)
#pragma unroll
    for (int r = 0; r < 4; ++r) {
      const int s = qw + mf * 16 + lg * 4 + r;
      const float inv = 1.0f / lrun[mf][r];
      const size_t base = ((size_t)(b * S_ + s)) * (H_ * HD_) + h * HD_;
#pragma unroll
      for (int n = 0; n < 8; ++n)
        O[base + n * 16 + lc] = f2bf(out[mf][n][r] * inv);
    }
}

// ---------------- launch ----------------
extern "C" void kernel_launch(void* const* d_in, const int* in_sizes, int n_in,
                              void* d_out, int out_size, void* d_ws, size_t ws_size,
                              hipStream_t stream) {
  const float* x     = (const float*)d_in[0];
  const float* freqs = (const float*)d_in[2];
  const float* wq    = (const float*)d_in[4];
  const float* wk    = (const float*)d_in[5];
  const float* wv    = (const float*)d_in[6];
  const float* wo    = (const float*)d_in[7];

  char* ws = (char*)d_ws;
  u16* xb   = (u16*)(ws + 0);
  u16* wqb  = (u16*)(ws + 33554432);
  u16* wkb  = (u16*)(ws + 67108864);
  u16* wvb  = (u16*)(ws + 75497472);
  u16* qlin = (u16*)(ws + 83886080);
  u16* klin = (u16*)(ws + 117440512);
  u16* vlin = (u16*)(ws + 125829120);
  u16* qr   = wqb;   // rope'd Q  [B][H][S][128]
  u16* kr   = wkb;   // rope'd K  [B][KVH][S][128]
  u16* vt   = wvb;   // V^T       [B][KVH][128][S]
  u16* aout = qlin;  // attention output [t][h*128+d]
  u16* wob  = xb;    // bf16 wo

  cast_kernel<<<8192, 256, 0, stream>>>(x, xb, 2097152);
  cast_kernel<<<8192, 256, 0, stream>>>(wq, wqb, 2097152);
  cast_kernel<<<2048, 256, 0, stream>>>(wk, wkb, 524288);
  cast_kernel<<<2048, 256, 0, stream>>>(wv, wvb, 524288);
  gemm_bt<false><<<dim3(32, 32), 256, 0, stream>>>(xb, wqb, qlin, 4096, 4096, 4096);
  gemm_bt<false><<<dim3(8, 32), 256, 0, stream>>>(xb, wkb, klin, 4096, 1024, 4096);
  gemm_bt<false><<<dim3(8, 32), 256, 0, stream>>>(xb, wvb, vlin, 4096, 1024, 4096);
  rope_kernel<32><<<32768, 256, 0, stream>>>(qlin, freqs, qr);
  rope_kernel<8><<<8192, 256, 0, stream>>>(klin, freqs, kr);
  vtrans_kernel<<<dim3(64, 4, 16), dim3(32, 8), 0, stream>>>(vlin, vt);
  attn_kernel<<<dim3(16, 32, 2), 256, 0, stream>>>(qr, kr, vt, aout);
  cast_kernel<<<8192, 256, 0, stream>>>(wo, wob, 2097152);
  gemm_bt<true><<<dim3(32, 32), 256, 0, stream>>>(aout, wob, d_out, 4096, 4096, 4096);
}

// Round 5
// 733.005 us; speedup vs baseline: 1.3405x; 1.0899x over previous
//
#include <hip/hip_runtime.h>
#include <cstdint>
#include <cstddef>

#define B_   2
#define S_   2048
#define D_   4096
#define H_   32
#define KVH_ 8
#define HD_  128

typedef unsigned short u16;
typedef short     bf16x8 __attribute__((ext_vector_type(8)));
typedef float     f32x4  __attribute__((ext_vector_type(4)));
typedef float     f32x16 __attribute__((ext_vector_type(16)));
typedef u16       u16x8  __attribute__((ext_vector_type(8)));
typedef uint32_t  u32x2  __attribute__((ext_vector_type(2)));
typedef uint32_t  u32x4  __attribute__((ext_vector_type(4)));

__device__ __forceinline__ u16 f2bf(float f) {
  union { float f; uint32_t u; } v; v.f = f;
  uint32_t u = v.u;
  return (u16)((u + 0x7fffu + ((u >> 16) & 1u)) >> 16);
}
__device__ __forceinline__ float bf2f(u16 h) {
  union { uint32_t u; float f; } v; v.u = ((uint32_t)h) << 16;
  return v.f;
}
__device__ __forceinline__ uint32_t pack2(float a, float b) {
  return (uint32_t)f2bf(a) | ((uint32_t)f2bf(b) << 16);
}

__device__ __forceinline__ void gl_lds16(const void* g, void* l) {
  __builtin_amdgcn_global_load_lds(
      (const __attribute__((address_space(1))) void*)g,
      (__attribute__((address_space(3))) void*)l, 16, 0, 0);
}

#define MFMA(a, b, c)  __builtin_amdgcn_mfma_f32_16x16x32_bf16((a), (b), (c), 0, 0, 0)
#define MFMA32(a, b, c) __builtin_amdgcn_mfma_f32_32x32x16_bf16((a), (b), (c), 0, 0, 0)
#define PLSWAP(x, y) asm volatile("v_permlane32_swap_b32 %0, %1" : "+v"(x), "+v"(y))

// ---------------- cast f32 -> bf16 ----------------
__global__ void cast_kernel(const float* __restrict__ in, u16* __restrict__ out, int n8) {
  int i = blockIdx.x * blockDim.x + threadIdx.x;
  if (i >= n8) return;
  const float4* p = (const float4*)in + (size_t)i * 2;
  float4 a = p[0], b = p[1];
  u16x8 r;
  r[0] = f2bf(a.x); r[1] = f2bf(a.y); r[2] = f2bf(a.z); r[3] = f2bf(a.w);
  r[4] = f2bf(b.x); r[5] = f2bf(b.y); r[6] = f2bf(b.z); r[7] = f2bf(b.w);
  *((u16x8*)out + i) = r;
}

// ---------------- GEMM-NT (unchanged, known-good) ----------------
template <bool OUT_F32>
__global__ __launch_bounds__(256, 2)
void gemm_bt(const u16* __restrict__ A, const u16* __restrict__ Bw,
             void* __restrict__ C, int M, int N, int K) {
  __shared__ u16 lA[128 * 32];
  __shared__ u16 lB[128 * 32];
  const int tid = threadIdx.x;
  const int w = tid >> 6, l = tid & 63;
  const int lc = l & 15, lg = l >> 4;
  const int bn = blockIdx.x, bm = blockIdx.y;
  const int wr = w >> 1, wc = w & 1;
  const u16* Ab = A + (size_t)(bm * 128) * K;
  const u16* Bb = Bw + (size_t)(bn * 128) * K;
  const int srow = l >> 2;
  const int scol = (l & 3) * 8;

  f32x4 acc[4][4];
#pragma unroll
  for (int i = 0; i < 4; ++i)
#pragma unroll
    for (int j = 0; j < 4; ++j) acc[i][j] = (f32x4){0.f, 0.f, 0.f, 0.f};

  const int nk = K >> 5;
  for (int kt = 0; kt < nk; ++kt) {
    const int k0 = kt * 32;
    __syncthreads();
#pragma unroll
    for (int i = 0; i < 2; ++i) {
      const int rowA = (w * 2 + i) * 16;
      gl_lds16(Ab + (size_t)(rowA + srow) * K + k0 + scol, &lA[rowA * 32]);
      gl_lds16(Bb + (size_t)(rowA + srow) * K + k0 + scol, &lB[rowA * 32]);
    }
    __syncthreads();
    bf16x8 af[4], bfr[4];
#pragma unroll
    for (int mi = 0; mi < 4; ++mi)
      af[mi] = *(const bf16x8*)&lA[(wr * 64 + mi * 16 + lc) * 32 + lg * 8];
#pragma unroll
    for (int ni = 0; ni < 4; ++ni)
      bfr[ni] = *(const bf16x8*)&lB[(wc * 64 + ni * 16 + lc) * 32 + lg * 8];
#pragma unroll
    for (int mi = 0; mi < 4; ++mi)
#pragma unroll
      for (int ni = 0; ni < 4; ++ni)
        acc[mi][ni] = MFMA(af[mi], bfr[ni], acc[mi][ni]);
  }

#pragma unroll
  for (int mi = 0; mi < 4; ++mi)
#pragma unroll
    for (int ni = 0; ni < 4; ++ni)
#pragma unroll
      for (int r = 0; r < 4; ++r) {
        const int row = bm * 128 + wr * 64 + mi * 16 + lg * 4 + r;
        const int col = bn * 128 + wc * 64 + ni * 16 + lc;
        if constexpr (OUT_F32)
          ((float*)C)[(size_t)row * N + col] = acc[mi][ni][r];
        else
          ((u16*)C)[(size_t)row * N + col] = f2bf(acc[mi][ni][r]);
      }
}

// ---------------- RoPE (scale folded into Q) ----------------
template <int NH>
__global__ void rope_kernel(const u16* __restrict__ lin, const float* __restrict__ fr,
                            u16* __restrict__ out, float scale) {
  int idx = blockIdx.x * 256 + threadIdx.x;
  const int total = B_ * S_ * NH * 64;
  if (idx >= total) return;
  const int i = idx & 63;
  const int h = (idx >> 6) % NH;
  const int t = idx / (64 * NH);
  const int s = t & (S_ - 1);
  const int b = t >> 11;
  const size_t src = (size_t)t * (NH * HD_) + h * HD_ + 2 * i;
  const float x0 = bf2f(lin[src]);
  const float x1 = bf2f(lin[src + 1]);
  const float2 cs = ((const float2*)fr)[s * 64 + i];
  const float o0 = (x0 * cs.x - x1 * cs.y) * scale;
  const float o1 = (x1 * cs.x + x0 * cs.y) * scale;
  const size_t dst = ((size_t)((b * NH + h) * S_ + s)) * HD_ + 2 * i;
  out[dst] = f2bf(o0);
  out[dst + 1] = f2bf(o1);
}

// ---------------- V transpose ----------------
__global__ void vtrans_kernel(const u16* __restrict__ vlin, u16* __restrict__ vt) {
  __shared__ u16 tile[32][33];
  const int tx = threadIdx.x, ty = threadIdx.y;  // (32, 8)
  const int s0 = blockIdx.x * 32;
  const int d0 = blockIdx.y * 32;
  const int bk = blockIdx.z;
  const int b = bk >> 3, kv = bk & 7;
#pragma unroll
  for (int r = 0; r < 4; ++r) {
    const int s = s0 + ty + r * 8;
    tile[ty + r * 8][tx] = vlin[((size_t)(b * S_ + s)) * (KVH_ * HD_) + kv * HD_ + d0 + tx];
  }
  __syncthreads();
#pragma unroll
  for (int r = 0; r < 4; ++r) {
    const int d = d0 + ty + r * 8;
    vt[((size_t)bk * HD_ + d) * S_ + s0 + tx] = tile[tx][ty + r * 8];
  }
}

// ---------------- causal GQA flash attention, 32x32 swapped-QK ----------------
// Block: 4 waves = 4 q-heads of ONE kv group, SAME 32 q-rows (zero imbalance).
// Q: [B][H][S][128] (pre-scaled by 1/sqrt(128)), K: [B][KVH][S][128],
// Vt: [B][KVH][128][S], O: [B][S][H*128]. KVBLK=64, double-buffered LDS.
// PV computed TRANSPOSED (D = V^T P^T) so D col = lane = q: softmax state
// and O-rescale stay lane-local. Epilogue transposes via LDS for coalescing.
__global__ __launch_bounds__(256, 2)
void attn_kernel(const u16* __restrict__ Q, const u16* __restrict__ K,
                 const u16* __restrict__ V, u16* __restrict__ O) {
  __shared__ u16 sK[2][64 * HD_];   // [key][d], 16B-chunk XOR-swizzled
  __shared__ u16 sV[2][HD_ * 64];   // [d][s],  16B-chunk XOR-swizzled
  const int tid = threadIdx.x;
  const int w = tid >> 6, l = tid & 63;
  const int hi = l >> 5, q32 = l & 31;
  const int qt = 63 - blockIdx.x;           // longest first
  const int kv = blockIdx.y, b = blockIdx.z;
  const int h = kv * 4 + w;
  const int qg = qt * 32 + q32;             // this lane's global q row
  const u16* Qp = Q + ((size_t)(b * H_ + h) * S_ + qt * 32) * HD_;
  const u16* Kp = K + ((size_t)(b * KVH_ + kv) * S_) * HD_;
  const u16* Vp = V + ((size_t)(b * KVH_ + kv) * HD_) * S_;

  // staging offsets: pre-swizzled global source, linear LDS dest
  int koff[4], voff[4];
#pragma unroll
  for (int i = 0; i < 4; ++i) {
    const int kr = w * 16 + i * 4 + (l >> 4);
    koff[i] = kr * HD_ + (((l & 15) ^ (kr & 7))) * 8;
    const int vr = w * 32 + i * 8 + (l >> 3);
    voff[i] = vr * S_ + (((l & 7) ^ (vr & 7))) * 8;
  }
  // swizzled read chunk offsets: global chunk g=(c*2+hi) at LDS chunk g^(row&7);
  // row&7 == l&7 for every row we read (q32, 32+q32, d*32+q32).
  int cx[8];
#pragma unroll
  for (int c = 0; c < 8; ++c) cx[c] = ((c * 2 + hi) ^ (l & 7)) * 8;

  // Q fragments (B-operand layout): lane holds Q[q32][ds*16 + hi*8 + j]
  bf16x8 qf[8];
#pragma unroll
  for (int ds = 0; ds < 8; ++ds)
    qf[ds] = *(const bf16x8*)(Qp + (size_t)q32 * HD_ + ds * 16 + hi * 8);
  asm volatile("s_waitcnt vmcnt(0)" ::: "memory");  // drain qf loads

  f32x16 out[4];
#pragma unroll
  for (int d = 0; d < 4; ++d)
#pragma unroll
    for (int r = 0; r < 16; ++r) out[d][r] = 0.f;
  float mrun = -1e30f, lrun = 0.f;

  auto STAGE = [&](int bufi, int ti) {
    const u16* kg = Kp + (size_t)ti * (64 * HD_);
    const u16* vg = Vp + (size_t)ti * 64;
#pragma unroll
    for (int i = 0; i < 4; ++i) {
      gl_lds16(kg + koff[i], &sK[bufi][(w * 16 + i * 4) * HD_]);
      gl_lds16(vg + voff[i], &sV[bufi][(w * 32 + i * 8) * 64]);
    }
  };

  const int nt = (qt >> 1) + 1;
  int cur = 0;
  STAGE(0, 0);

  for (int t = 0; t < nt; ++t) {
    if (t + 1 < nt) {
      STAGE(cur ^ 1, t + 1);
      asm volatile("s_waitcnt vmcnt(8)" ::: "memory");
    } else {
      asm volatile("s_waitcnt vmcnt(0)" ::: "memory");
    }
    __builtin_amdgcn_s_barrier();
    asm volatile("" ::: "memory");

    // ---- S^T = K Q^T : D[key][q], col=lane&31=q, row=crow(r,hi)=key
    f32x16 sc0, sc1;
#pragma unroll
    for (int r = 0; r < 16; ++r) { sc0[r] = 0.f; sc1[r] = 0.f; }
    __builtin_amdgcn_s_setprio(1);
#pragma unroll
    for (int ds = 0; ds < 8; ++ds) {
      bf16x8 kf0 = *(const bf16x8*)&sK[cur][q32 * HD_ + cx[ds]];
      bf16x8 kf1 = *(const bf16x8*)&sK[cur][(32 + q32) * HD_ + cx[ds]];
      sc0 = MFMA32(kf0, qf[ds], sc0);
      sc1 = MFMA32(kf1, qf[ds], sc1);
    }
    __builtin_amdgcn_s_setprio(0);

    // ---- causal mask (scale folded into Q)
    const bool diag = (t == nt - 1);
    float p0[16], p1[16];
#pragma unroll
    for (int r = 0; r < 16; ++r) {
      const int krow = (r & 3) + 8 * (r >> 2) + 4 * hi;
      float v0 = sc0[r], v1 = sc1[r];
      if (diag) {
        if (t * 64 + krow > qg) v0 = -1e9f;
        if (t * 64 + 32 + krow > qg) v1 = -1e9f;
      }
      p0[r] = v0; p1[r] = v1;
    }
    // ---- online softmax: row q32 is lane-local (16+16 vals) + partner lane^32
    float rm = -1e30f;
#pragma unroll
    for (int r = 0; r < 16; ++r) rm = fmaxf(rm, fmaxf(p0[r], p1[r]));
    rm = fmaxf(rm, __shfl_xor(rm, 32, 64));
    const float mnew = fmaxf(mrun, rm);
    const float alpha = __expf(mrun - mnew);
    mrun = mnew;
    lrun *= alpha;
#pragma unroll
    for (int d = 0; d < 4; ++d) out[d] *= alpha;   // col=q32: lane-local, correct
    float sum = 0.f;
#pragma unroll
    for (int r = 0; r < 16; ++r) {
      p0[r] = __expf(p0[r] - mnew);
      p1[r] = __expf(p1[r] - mnew);
      sum += p0[r] + p1[r];
    }
    sum += __shfl_xor(sum, 32, 64);
    lrun += sum;
    // ---- pack P to bf16 pairs; build P^T fragments via permlane32_swap
    // PLSWAP(x,y): x <- (x_lo, y_lo), y <- (x_hi_old, y_hi) across lane^32.
    uint32_t pk0[8], pk1[8];
#pragma unroll
    for (int g = 0; g < 4; ++g) {
      pk0[2 * g]     = pack2(p0[4 * g], p0[4 * g + 1]);
      pk0[2 * g + 1] = pack2(p0[4 * g + 2], p0[4 * g + 3]);
      pk1[2 * g]     = pack2(p1[4 * g], p1[4 * g + 1]);
      pk1[2 * g + 1] = pack2(p1[4 * g + 2], p1[4 * g + 3]);
    }
    PLSWAP(pk0[0], pk0[2]); PLSWAP(pk0[1], pk0[3]);
    PLSWAP(pk0[4], pk0[6]); PLSWAP(pk0[5], pk0[7]);
    PLSWAP(pk1[0], pk1[2]); PLSWAP(pk1[1], pk1[3]);
    PLSWAP(pk1[4], pk1[6]); PLSWAP(pk1[5], pk1[7]);
    bf16x8 pa[4];
    pa[0] = __builtin_bit_cast(bf16x8, (u32x4){pk0[0], pk0[1], pk0[2], pk0[3]});
    pa[1] = __builtin_bit_cast(bf16x8, (u32x4){pk0[4], pk0[5], pk0[6], pk0[7]});
    pa[2] = __builtin_bit_cast(bf16x8, (u32x4){pk1[0], pk1[1], pk1[2], pk1[3]});
    pa[3] = __builtin_bit_cast(bf16x8, (u32x4){pk1[4], pk1[5], pk1[6], pk1[7]});
    // ---- O^T acc += V^T P^T : A = V^T frag (rows=dd), B = P^T frag (cols=q).
    // D col = lane&31 = q32  -> rescale/normalize lane-local.
    __builtin_amdgcn_s_setprio(1);
#pragma unroll
    for (int d = 0; d < 4; ++d) {
      const int vbase = (d * 32 + q32) * 64;
#pragma unroll
      for (int kk = 0; kk < 4; ++kk) {
        bf16x8 vf = *(const bf16x8*)&sV[cur][vbase + cx[kk]];
        out[d] = MFMA32(vf, pa[kk], out[d]);
      }
    }
    __builtin_amdgcn_s_setprio(0);
    asm volatile("" ::: "memory");
    __builtin_amdgcn_s_barrier();
    cur ^= 1;
  }

  // ---- epilogue: out[d][r] = O[q32][d*32 + crow(r,hi)]; LDS-stage per wave
  // (sK is free now; all waves past last barrier) to coalesce the row store.
  const float inv = 1.0f / lrun;
  u16* myS = ((u16*)sK) + w * 4096;   // 32 q-rows x 128 dims, 8B-granule swizzled
#pragma unroll
  for (int d = 0; d < 4; ++d)
#pragma unroll
    for (int rq = 0; rq < 4; ++rq) {
      u32x2 pw;
      pw[0] = pack2(out[d][rq * 4 + 0] * inv, out[d][rq * 4 + 1] * inv);
      pw[1] = pack2(out[d][rq * 4 + 2] * inv, out[d][rq * 4 + 3] * inv);
      // dims d*32 + 8*rq + 4*hi + (0..3); granule idx (d*8+rq*2+hi) ^ (q32&15)
      const int gin = (d * 8 + rq * 2 + hi) ^ (q32 & 15);
      *(u32x2*)&myS[q32 * 128 + gin * 4] = pw;
    }
  asm volatile("s_waitcnt lgkmcnt(0)" ::: "memory");
  __builtin_amdgcn_sched_barrier(0);
  const int rr = l >> 4;   // 0..3
  const int cc = l & 15;   // 16B chunk within a row
#pragma unroll
  for (int p = 0; p < 8; ++p) {
    const int q = p * 4 + rr;
    const int ga = (2 * cc) ^ (q & 15);
    const int gb = (2 * cc + 1) ^ (q & 15);
    u32x2 va = *(const u32x2*)&myS[q * 128 + ga * 4];
    u32x2 vb = *(const u32x2*)&myS[q * 128 + gb * 4];
    u32x4 val = {va[0], va[1], vb[0], vb[1]};
    *(u32x4*)&O[((size_t)(b * S_ + qt * 32 + q)) * (H_ * HD_) + h * HD_ + cc * 8] = val;
  }
}

// ---------------- launch ----------------
extern "C" void kernel_launch(void* const* d_in, const int* in_sizes, int n_in,
                              void* d_out, int out_size, void* d_ws, size_t ws_size,
                              hipStream_t stream) {
  const float* x     = (const float*)d_in[0];
  const float* freqs = (const float*)d_in[2];
  const float* wq    = (const float*)d_in[4];
  const float* wk    = (const float*)d_in[5];
  const float* wv    = (const float*)d_in[6];
  const float* wo    = (const float*)d_in[7];

  char* ws = (char*)d_ws;
  u16* xb   = (u16*)(ws + 0);
  u16* wqb  = (u16*)(ws + 33554432);
  u16* wkb  = (u16*)(ws + 67108864);
  u16* wvb  = (u16*)(ws + 75497472);
  u16* qlin = (u16*)(ws + 83886080);
  u16* klin = (u16*)(ws + 117440512);
  u16* vlin = (u16*)(ws + 125829120);
  u16* qr   = wqb;   // rope'd Q (pre-scaled)
  u16* kr   = wkb;   // rope'd K
  u16* vt   = wvb;   // V^T
  u16* aout = qlin;  // attention output
  u16* wob  = xb;    // bf16 wo

  cast_kernel<<<8192, 256, 0, stream>>>(x, xb, 2097152);
  cast_kernel<<<8192, 256, 0, stream>>>(wq, wqb, 2097152);
  cast_kernel<<<2048, 256, 0, stream>>>(wk, wkb, 524288);
  cast_kernel<<<2048, 256, 0, stream>>>(wv, wvb, 524288);
  gemm_bt<false><<<dim3(32, 32), 256, 0, stream>>>(xb, wqb, qlin, 4096, 4096, 4096);
  gemm_bt<false><<<dim3(8, 32), 256, 0, stream>>>(xb, wkb, klin, 4096, 1024, 4096);
  gemm_bt<false><<<dim3(8, 32), 256, 0, stream>>>(xb, wvb, vlin, 4096, 1024, 4096);
  rope_kernel<32><<<32768, 256, 0, stream>>>(qlin, freqs, qr, 0.08838834764831845f);
  rope_kernel<8><<<8192, 256, 0, stream>>>(klin, freqs, kr, 1.0f);
  vtrans_kernel<<<dim3(64, 4, 16), dim3(32, 8), 0, stream>>>(vlin, vt);
  attn_kernel<<<dim3(64, 8, 2), 256, 0, stream>>>(qr, kr, vt, aout);
  cast_kernel<<<8192, 256, 0, stream>>>(wo, wob, 2097152);
  gemm_bt<true><<<dim3(32, 32), 256, 0, stream>>>(aout, wob, d_out, 4096, 4096, 4096);
}

// Round 6
// 706.103 us; speedup vs baseline: 1.3916x; 1.0381x over previous
//
#include <hip/hip_runtime.h>
#include <cstdint>
#include <cstddef>

#define B_   2
#define S_   2048
#define D_   4096
#define H_   32
#define KVH_ 8
#define HD_  128

typedef unsigned short u16;
typedef short     bf16x8 __attribute__((ext_vector_type(8)));
typedef float     f32x4  __attribute__((ext_vector_type(4)));
typedef float     f32x16 __attribute__((ext_vector_type(16)));
typedef u16       u16x8  __attribute__((ext_vector_type(8)));
typedef uint32_t  u32x2  __attribute__((ext_vector_type(2)));
typedef uint32_t  u32x4  __attribute__((ext_vector_type(4)));

__device__ __forceinline__ u16 f2bf(float f) {
  union { float f; uint32_t u; } v; v.f = f;
  uint32_t u = v.u;
  return (u16)((u + 0x7fffu + ((u >> 16) & 1u)) >> 16);
}
__device__ __forceinline__ float bf2f(u16 h) {
  union { uint32_t u; float f; } v; v.u = ((uint32_t)h) << 16;
  return v.f;
}
__device__ __forceinline__ uint32_t pack2(float a, float b) {
  return (uint32_t)f2bf(a) | ((uint32_t)f2bf(b) << 16);
}

__device__ __forceinline__ void gl_lds16(const void* g, void* l) {
  __builtin_amdgcn_global_load_lds(
      (const __attribute__((address_space(1))) void*)g,
      (__attribute__((address_space(3))) void*)l, 16, 0, 0);
}

#define MFMA(a, b, c)  __builtin_amdgcn_mfma_f32_16x16x32_bf16((a), (b), (c), 0, 0, 0)
#define MFMA32(a, b, c) __builtin_amdgcn_mfma_f32_32x32x16_bf16((a), (b), (c), 0, 0, 0)
#define PLSWAP(x, y) asm volatile("v_permlane32_swap_b32 %0, %1" : "+v"(x), "+v"(y))

// ---------------- cast f32 -> bf16 ----------------
__global__ void cast_kernel(const float* __restrict__ in, u16* __restrict__ out, int n8) {
  int i = blockIdx.x * blockDim.x + threadIdx.x;
  if (i >= n8) return;
  const float4* p = (const float4*)in + (size_t)i * 2;
  float4 a = p[0], b = p[1];
  u16x8 r;
  r[0] = f2bf(a.x); r[1] = f2bf(a.y); r[2] = f2bf(a.z); r[3] = f2bf(a.w);
  r[4] = f2bf(b.x); r[5] = f2bf(b.y); r[6] = f2bf(b.z); r[7] = f2bf(b.w);
  *((u16x8*)out + i) = r;
}

// ---------------- GEMM-NT 128^2 (known-good; used for K/V proj) ----------------
template <bool OUT_F32>
__global__ __launch_bounds__(256, 2)
void gemm_bt(const u16* __restrict__ A, const u16* __restrict__ Bw,
             void* __restrict__ C, int M, int N, int K) {
  __shared__ u16 lA[128 * 32];
  __shared__ u16 lB[128 * 32];
  const int tid = threadIdx.x;
  const int w = tid >> 6, l = tid & 63;
  const int lc = l & 15, lg = l >> 4;
  const int bn = blockIdx.x, bm = blockIdx.y;
  const int wr = w >> 1, wc = w & 1;
  const u16* Ab = A + (size_t)(bm * 128) * K;
  const u16* Bb = Bw + (size_t)(bn * 128) * K;
  const int srow = l >> 2;
  const int scol = (l & 3) * 8;

  f32x4 acc[4][4];
#pragma unroll
  for (int i = 0; i < 4; ++i)
#pragma unroll
    for (int j = 0; j < 4; ++j) acc[i][j] = (f32x4){0.f, 0.f, 0.f, 0.f};

  const int nk = K >> 5;
  for (int kt = 0; kt < nk; ++kt) {
    const int k0 = kt * 32;
    __syncthreads();
#pragma unroll
    for (int i = 0; i < 2; ++i) {
      const int rowA = (w * 2 + i) * 16;
      gl_lds16(Ab + (size_t)(rowA + srow) * K + k0 + scol, &lA[rowA * 32]);
      gl_lds16(Bb + (size_t)(rowA + srow) * K + k0 + scol, &lB[rowA * 32]);
    }
    __syncthreads();
    bf16x8 af[4], bfr[4];
#pragma unroll
    for (int mi = 0; mi < 4; ++mi)
      af[mi] = *(const bf16x8*)&lA[(wr * 64 + mi * 16 + lc) * 32 + lg * 8];
#pragma unroll
    for (int ni = 0; ni < 4; ++ni)
      bfr[ni] = *(const bf16x8*)&lB[(wc * 64 + ni * 16 + lc) * 32 + lg * 8];
#pragma unroll
    for (int mi = 0; mi < 4; ++mi)
#pragma unroll
      for (int ni = 0; ni < 4; ++ni)
        acc[mi][ni] = MFMA(af[mi], bfr[ni], acc[mi][ni]);
  }

#pragma unroll
  for (int mi = 0; mi < 4; ++mi)
#pragma unroll
    for (int ni = 0; ni < 4; ++ni)
#pragma unroll
      for (int r = 0; r < 4; ++r) {
        const int row = bm * 128 + wr * 64 + mi * 16 + lg * 4 + r;
        const int col = bn * 128 + wc * 64 + ni * 16 + lc;
        if constexpr (OUT_F32)
          ((float*)C)[(size_t)row * N + col] = acc[mi][ni][r];
        else
          ((u16*)C)[(size_t)row * N + col] = f2bf(acc[mi][ni][r]);
      }
}

// ---------------- GEMM-NT 256^2, BK=64, 8 waves, 4-phase pipelined ------------
// C[M][N] = A[M][K] * B[N][K]^T, bf16 in. LDS 128 KiB (A,B double-buffered,
// 16B-chunk XOR swizzle chunk^=(row&7)). Per K-tile: 4 phases, each
// {12 ds_read_b128 || stage -> barrier -> lgkmcnt(0) -> 16 MFMA -> barrier},
// vmcnt(0) only at phase 3 (newest prefetch >= 1 phase old). XCD swizzle.
template <bool OUT_F32>
__global__ __launch_bounds__(512, 2)
void gemm256_bt(const u16* __restrict__ A, const u16* __restrict__ Bw,
                void* __restrict__ C, int M, int N, int K) {
  __shared__ u16 sA[2 * 256 * 64];
  __shared__ u16 sB[2 * 256 * 64];
  const int tid = threadIdx.x;
  const int w = tid >> 6, l = tid & 63;
  const int lc = l & 15, lg = l >> 4;
  const int wm = w >> 2, wn = w & 3;          // 2 x 4 wave grid
  // bijective XCD swizzle over 256 blocks (nwg % 8 == 0)
  const int nbn = N >> 8;
  const int nwg = (M >> 8) * nbn;
  const int cpx = nwg >> 3;
  const int lin = blockIdx.x;
  const int swz = (lin & 7) * cpx + (lin >> 3);
  const int bm = swz / nbn, bn = swz % nbn;
  const u16* Ab = A + (size_t)(bm * 256) * K;
  const u16* Bb = Bw + (size_t)(bn * 256) * K;
  const int lr = l >> 3;                       // staging: row within 8-row group
  const int scc = ((l & 7) ^ lr) * 8;          // staging: pre-swizzled src chunk
  int cxg[2];                                  // read: LDS chunk for kk, ^= row&7
#pragma unroll
  for (int kk = 0; kk < 2; ++kk) cxg[kk] = ((kk * 4 + lg) ^ (lc & 7)) * 8;

  f32x4 acc[8][4];
#pragma unroll
  for (int i = 0; i < 8; ++i)
#pragma unroll
    for (int j = 0; j < 4; ++j) acc[i][j] = (f32x4){0.f, 0.f, 0.f, 0.f};

  // stage one 128-row half of A or B tile t1 into buf (2 issues per wave)
  auto STAGEA = [&](int buf, int t1, int h) {
    const int k0 = t1 * 64;
#pragma unroll
    for (int j = 0; j < 2; ++j) {
      const int r0 = h * 128 + w * 16 + j * 8;
      gl_lds16(Ab + (size_t)(r0 + lr) * K + k0 + scc, &sA[buf * 16384 + r0 * 64]);
    }
  };
  auto STAGEB = [&](int buf, int t1, int h) {
    const int k0 = t1 * 64;
#pragma unroll
    for (int j = 0; j < 2; ++j) {
      const int r0 = h * 128 + w * 16 + j * 8;
      gl_lds16(Bb + (size_t)(r0 + lr) * K + k0 + scc, &sB[buf * 16384 + r0 * 64]);
    }
  };

  // prologue: fully stage tile 0 into buf 0
  STAGEA(0, 0, 0); STAGEA(0, 0, 1);
  STAGEB(0, 0, 0); STAGEB(0, 0, 1);
  asm volatile("s_waitcnt vmcnt(0)" ::: "memory");
  __builtin_amdgcn_s_barrier();
  asm volatile("" ::: "memory");

  const int nk = K >> 6;
  for (int t = 0; t < nk; ++t) {
    const int cur = t & 1;
    const int cb = cur * 16384;
    const int nb = (cur ^ 1) * 16384;
    (void)nb;
    const bool pf = (t + 1 < nk);
#pragma unroll
    for (int p = 0; p < 4; ++p) {
      const int qm = p >> 1, qn = p & 1;
      // ---- ds-load this quadrant's fragments (8 A + 4 B x b128)
      bf16x8 af[4][2], bfr[2][2];
#pragma unroll
      for (int mi = 0; mi < 4; ++mi)
#pragma unroll
        for (int kk = 0; kk < 2; ++kk)
          af[mi][kk] = *(const bf16x8*)
              &sA[cb + (wm * 128 + qm * 64 + mi * 16 + lc) * 64 + cxg[kk]];
#pragma unroll
      for (int ni = 0; ni < 2; ++ni)
#pragma unroll
        for (int kk = 0; kk < 2; ++kk)
          bfr[ni][kk] = *(const bf16x8*)
              &sB[cb + (wn * 64 + qn * 32 + ni * 16 + lc) * 64 + cxg[kk]];
      // ---- prefetch next tile: A0,A1 @p0; B0 @p1; B1 @p2
      if (pf) {
        if (p == 0) { STAGEA(cur ^ 1, t + 1, 0); STAGEA(cur ^ 1, t + 1, 1); }
        if (p == 1) { STAGEB(cur ^ 1, t + 1, 0); }
        if (p == 2) { STAGEB(cur ^ 1, t + 1, 1); }
      }
      __builtin_amdgcn_s_barrier();
      asm volatile("s_waitcnt lgkmcnt(0)" ::: "memory");
      __builtin_amdgcn_sched_barrier(0);
      __builtin_amdgcn_s_setprio(1);
#pragma unroll
      for (int kk = 0; kk < 2; ++kk)
#pragma unroll
        for (int mi = 0; mi < 4; ++mi)
#pragma unroll
          for (int ni = 0; ni < 2; ++ni)
            acc[qm * 4 + mi][qn * 2 + ni] =
                MFMA(af[mi][kk], bfr[ni][kk], acc[qm * 4 + mi][qn * 2 + ni]);
      __builtin_amdgcn_s_setprio(0);
      if (p == 3) asm volatile("s_waitcnt vmcnt(0)" ::: "memory");
      __builtin_amdgcn_s_barrier();
      asm volatile("" ::: "memory");
    }
  }

  // ---- epilogue
#pragma unroll
  for (int mi = 0; mi < 8; ++mi)
#pragma unroll
    for (int ni = 0; ni < 4; ++ni)
#pragma unroll
      for (int r = 0; r < 4; ++r) {
        const int row = bm * 256 + wm * 128 + mi * 16 + lg * 4 + r;
        const int col = bn * 256 + wn * 64 + ni * 16 + lc;
        if constexpr (OUT_F32)
          ((float*)C)[(size_t)row * N + col] = acc[mi][ni][r];
        else
          ((u16*)C)[(size_t)row * N + col] = f2bf(acc[mi][ni][r]);
      }
}

// ---------------- RoPE (scale folded into Q) ----------------
template <int NH>
__global__ void rope_kernel(const u16* __restrict__ lin, const float* __restrict__ fr,
                            u16* __restrict__ out, float scale) {
  int idx = blockIdx.x * 256 + threadIdx.x;
  const int total = B_ * S_ * NH * 64;
  if (idx >= total) return;
  const int i = idx & 63;
  const int h = (idx >> 6) % NH;
  const int t = idx / (64 * NH);
  const int s = t & (S_ - 1);
  const int b = t >> 11;
  const size_t src = (size_t)t * (NH * HD_) + h * HD_ + 2 * i;
  const float x0 = bf2f(lin[src]);
  const float x1 = bf2f(lin[src + 1]);
  const float2 cs = ((const float2*)fr)[s * 64 + i];
  const float o0 = (x0 * cs.x - x1 * cs.y) * scale;
  const float o1 = (x1 * cs.x + x0 * cs.y) * scale;
  const size_t dst = ((size_t)((b * NH + h) * S_ + s)) * HD_ + 2 * i;
  out[dst] = f2bf(o0);
  out[dst + 1] = f2bf(o1);
}

// ---------------- V transpose ----------------
__global__ void vtrans_kernel(const u16* __restrict__ vlin, u16* __restrict__ vt) {
  __shared__ u16 tile[32][33];
  const int tx = threadIdx.x, ty = threadIdx.y;  // (32, 8)
  const int s0 = blockIdx.x * 32;
  const int d0 = blockIdx.y * 32;
  const int bk = blockIdx.z;
  const int b = bk >> 3, kv = bk & 7;
#pragma unroll
  for (int r = 0; r < 4; ++r) {
    const int s = s0 + ty + r * 8;
    tile[ty + r * 8][tx] = vlin[((size_t)(b * S_ + s)) * (KVH_ * HD_) + kv * HD_ + d0 + tx];
  }
  __syncthreads();
#pragma unroll
  for (int r = 0; r < 4; ++r) {
    const int d = d0 + ty + r * 8;
    vt[((size_t)bk * HD_ + d) * S_ + s0 + tx] = tile[tx][ty + r * 8];
  }
}

// ---------------- causal GQA flash attention (unchanged from round 5) ---------
__global__ __launch_bounds__(256, 2)
void attn_kernel(const u16* __restrict__ Q, const u16* __restrict__ K,
                 const u16* __restrict__ V, u16* __restrict__ O) {
  __shared__ u16 sK[2][64 * HD_];   // [key][d], 16B-chunk XOR-swizzled
  __shared__ u16 sV[2][HD_ * 64];   // [d][s],  16B-chunk XOR-swizzled
  const int tid = threadIdx.x;
  const int w = tid >> 6, l = tid & 63;
  const int hi = l >> 5, q32 = l & 31;
  const int qt = 63 - blockIdx.x;           // longest first
  const int kv = blockIdx.y, b = blockIdx.z;
  const int h = kv * 4 + w;
  const int qg = qt * 32 + q32;
  const u16* Qp = Q + ((size_t)(b * H_ + h) * S_ + qt * 32) * HD_;
  const u16* Kp = K + ((size_t)(b * KVH_ + kv) * S_) * HD_;
  const u16* Vp = V + ((size_t)(b * KVH_ + kv) * HD_) * S_;

  int koff[4], voff[4];
#pragma unroll
  for (int i = 0; i < 4; ++i) {
    const int kr = w * 16 + i * 4 + (l >> 4);
    koff[i] = kr * HD_ + (((l & 15) ^ (kr & 7))) * 8;
    const int vr = w * 32 + i * 8 + (l >> 3);
    voff[i] = vr * S_ + (((l & 7) ^ (vr & 7))) * 8;
  }
  int cx[8];
#pragma unroll
  for (int c = 0; c < 8; ++c) cx[c] = ((c * 2 + hi) ^ (l & 7)) * 8;

  bf16x8 qf[8];
#pragma unroll
  for (int ds = 0; ds < 8; ++ds)
    qf[ds] = *(const bf16x8*)(Qp + (size_t)q32 * HD_ + ds * 16 + hi * 8);
  asm volatile("s_waitcnt vmcnt(0)" ::: "memory");

  f32x16 out[4];
#pragma unroll
  for (int d = 0; d < 4; ++d)
#pragma unroll
    for (int r = 0; r < 16; ++r) out[d][r] = 0.f;
  float mrun = -1e30f, lrun = 0.f;

  auto STAGE = [&](int bufi, int ti) {
    const u16* kg = Kp + (size_t)ti * (64 * HD_);
    const u16* vg = Vp + (size_t)ti * 64;
#pragma unroll
    for (int i = 0; i < 4; ++i) {
      gl_lds16(kg + koff[i], &sK[bufi][(w * 16 + i * 4) * HD_]);
      gl_lds16(vg + voff[i], &sV[bufi][(w * 32 + i * 8) * 64]);
    }
  };

  const int nt = (qt >> 1) + 1;
  int cur = 0;
  STAGE(0, 0);

  for (int t = 0; t < nt; ++t) {
    if (t + 1 < nt) {
      STAGE(cur ^ 1, t + 1);
      asm volatile("s_waitcnt vmcnt(8)" ::: "memory");
    } else {
      asm volatile("s_waitcnt vmcnt(0)" ::: "memory");
    }
    __builtin_amdgcn_s_barrier();
    asm volatile("" ::: "memory");

    f32x16 sc0, sc1;
#pragma unroll
    for (int r = 0; r < 16; ++r) { sc0[r] = 0.f; sc1[r] = 0.f; }
    __builtin_amdgcn_s_setprio(1);
#pragma unroll
    for (int ds = 0; ds < 8; ++ds) {
      bf16x8 kf0 = *(const bf16x8*)&sK[cur][q32 * HD_ + cx[ds]];
      bf16x8 kf1 = *(const bf16x8*)&sK[cur][(32 + q32) * HD_ + cx[ds]];
      sc0 = MFMA32(kf0, qf[ds], sc0);
      sc1 = MFMA32(kf1, qf[ds], sc1);
    }
    __builtin_amdgcn_s_setprio(0);

    const bool diag = (t == nt - 1);
    float p0[16], p1[16];
#pragma unroll
    for (int r = 0; r < 16; ++r) {
      const int krow = (r & 3) + 8 * (r >> 2) + 4 * hi;
      float v0 = sc0[r], v1 = sc1[r];
      if (diag) {
        if (t * 64 + krow > qg) v0 = -1e9f;
        if (t * 64 + 32 + krow > qg) v1 = -1e9f;
      }
      p0[r] = v0; p1[r] = v1;
    }
    float rm = -1e30f;
#pragma unroll
    for (int r = 0; r < 16; ++r) rm = fmaxf(rm, fmaxf(p0[r], p1[r]));
    rm = fmaxf(rm, __shfl_xor(rm, 32, 64));
    const float mnew = fmaxf(mrun, rm);
    const float alpha = __expf(mrun - mnew);
    mrun = mnew;
    lrun *= alpha;
#pragma unroll
    for (int d = 0; d < 4; ++d) out[d] *= alpha;
    float sum = 0.f;
#pragma unroll
    for (int r = 0; r < 16; ++r) {
      p0[r] = __expf(p0[r] - mnew);
      p1[r] = __expf(p1[r] - mnew);
      sum += p0[r] + p1[r];
    }
    sum += __shfl_xor(sum, 32, 64);
    lrun += sum;
    uint32_t pk0[8], pk1[8];
#pragma unroll
    for (int g = 0; g < 4; ++g) {
      pk0[2 * g]     = pack2(p0[4 * g], p0[4 * g + 1]);
      pk0[2 * g + 1] = pack2(p0[4 * g + 2], p0[4 * g + 3]);
      pk1[2 * g]     = pack2(p1[4 * g], p1[4 * g + 1]);
      pk1[2 * g + 1] = pack2(p1[4 * g + 2], p1[4 * g + 3]);
    }
    PLSWAP(pk0[0], pk0[2]); PLSWAP(pk0[1], pk0[3]);
    PLSWAP(pk0[4], pk0[6]); PLSWAP(pk0[5], pk0[7]);
    PLSWAP(pk1[0], pk1[2]); PLSWAP(pk1[1], pk1[3]);
    PLSWAP(pk1[4], pk1[6]); PLSWAP(pk1[5], pk1[7]);
    bf16x8 pa[4];
    pa[0] = __builtin_bit_cast(bf16x8, (u32x4){pk0[0], pk0[1], pk0[2], pk0[3]});
    pa[1] = __builtin_bit_cast(bf16x8, (u32x4){pk0[4], pk0[5], pk0[6], pk0[7]});
    pa[2] = __builtin_bit_cast(bf16x8, (u32x4){pk1[0], pk1[1], pk1[2], pk1[3]});
    pa[3] = __builtin_bit_cast(bf16x8, (u32x4){pk1[4], pk1[5], pk1[6], pk1[7]});
    __builtin_amdgcn_s_setprio(1);
#pragma unroll
    for (int d = 0; d < 4; ++d) {
      const int vbase = (d * 32 + q32) * 64;
#pragma unroll
      for (int kk = 0; kk < 4; ++kk) {
        bf16x8 vf = *(const bf16x8*)&sV[cur][vbase + cx[kk]];
        out[d] = MFMA32(vf, pa[kk], out[d]);
      }
    }
    __builtin_amdgcn_s_setprio(0);
    asm volatile("" ::: "memory");
    __builtin_amdgcn_s_barrier();
    cur ^= 1;
  }

  const float inv = 1.0f / lrun;
  u16* myS = ((u16*)sK) + w * 4096;
#pragma unroll
  for (int d = 0; d < 4; ++d)
#pragma unroll
    for (int rq = 0; rq < 4; ++rq) {
      u32x2 pw;
      pw[0] = pack2(out[d][rq * 4 + 0] * inv, out[d][rq * 4 + 1] * inv);
      pw[1] = pack2(out[d][rq * 4 + 2] * inv, out[d][rq * 4 + 3] * inv);
      const int gin = (d * 8 + rq * 2 + hi) ^ (q32 & 15);
      *(u32x2*)&myS[q32 * 128 + gin * 4] = pw;
    }
  asm volatile("s_waitcnt lgkmcnt(0)" ::: "memory");
  __builtin_amdgcn_sched_barrier(0);
  const int rr = l >> 4;
  const int cc = l & 15;
#pragma unroll
  for (int p = 0; p < 8; ++p) {
    const int q = p * 4 + rr;
    const int ga = (2 * cc) ^ (q & 15);
    const int gb = (2 * cc + 1) ^ (q & 15);
    u32x2 va = *(const u32x2*)&myS[q * 128 + ga * 4];
    u32x2 vb = *(const u32x2*)&myS[q * 128 + gb * 4];
    u32x4 val = {va[0], va[1], vb[0], vb[1]};
    *(u32x4*)&O[((size_t)(b * S_ + qt * 32 + q)) * (H_ * HD_) + h * HD_ + cc * 8] = val;
  }
}

// ---------------- launch ----------------
extern "C" void kernel_launch(void* const* d_in, const int* in_sizes, int n_in,
                              void* d_out, int out_size, void* d_ws, size_t ws_size,
                              hipStream_t stream) {
  const float* x     = (const float*)d_in[0];
  const float* freqs = (const float*)d_in[2];
  const float* wq    = (const float*)d_in[4];
  const float* wk    = (const float*)d_in[5];
  const float* wv    = (const float*)d_in[6];
  const float* wo    = (const float*)d_in[7];

  char* ws = (char*)d_ws;
  u16* xb   = (u16*)(ws + 0);
  u16* wqb  = (u16*)(ws + 33554432);
  u16* wkb  = (u16*)(ws + 67108864);
  u16* wvb  = (u16*)(ws + 75497472);
  u16* qlin = (u16*)(ws + 83886080);
  u16* klin = (u16*)(ws + 117440512);
  u16* vlin = (u16*)(ws + 125829120);
  u16* qr   = wqb;   // rope'd Q (pre-scaled)
  u16* kr   = wkb;   // rope'd K
  u16* vt   = wvb;   // V^T
  u16* aout = qlin;  // attention output
  u16* wob  = xb;    // bf16 wo

  cast_kernel<<<8192, 256, 0, stream>>>(x, xb, 2097152);
  cast_kernel<<<8192, 256, 0, stream>>>(wq, wqb, 2097152);
  cast_kernel<<<2048, 256, 0, stream>>>(wk, wkb, 524288);
  cast_kernel<<<2048, 256, 0, stream>>>(wv, wvb, 524288);
  gemm256_bt<false><<<256, 512, 0, stream>>>(xb, wqb, qlin, 4096, 4096, 4096);
  gemm_bt<false><<<dim3(8, 32), 256, 0, stream>>>(xb, wkb, klin, 4096, 1024, 4096);
  gemm_bt<false><<<dim3(8, 32), 256, 0, stream>>>(xb, wvb, vlin, 4096, 1024, 4096);
  rope_kernel<32><<<32768, 256, 0, stream>>>(qlin, freqs, qr, 0.08838834764831845f);
  rope_kernel<8><<<8192, 256, 0, stream>>>(klin, freqs, kr, 1.0f);
  vtrans_kernel<<<dim3(64, 4, 16), dim3(32, 8), 0, stream>>>(vlin, vt);
  attn_kernel<<<dim3(64, 8, 2), 256, 0, stream>>>(qr, kr, vt, aout);
  cast_kernel<<<8192, 256, 0, stream>>>(wo, wob, 2097152);
  gemm256_bt<true><<<256, 512, 0, stream>>>(aout, wob, d_out, 4096, 4096, 4096);
}

// Round 7
// 676.521 us; speedup vs baseline: 1.4524x; 1.0437x over previous
//
#include <hip/hip_runtime.h>
#include <cstdint>
#include <cstddef>

#define B_   2
#define S_   2048
#define D_   4096
#define H_   32
#define KVH_ 8
#define HD_  128

typedef unsigned short u16;
typedef short     bf16x8 __attribute__((ext_vector_type(8)));
typedef float     f32x4  __attribute__((ext_vector_type(4)));
typedef float     f32x16 __attribute__((ext_vector_type(16)));
typedef u16       u16x8  __attribute__((ext_vector_type(8)));
typedef uint32_t  u32x2  __attribute__((ext_vector_type(2)));
typedef uint32_t  u32x4  __attribute__((ext_vector_type(4)));

__device__ __forceinline__ u16 f2bf(float f) {
  union { float f; uint32_t u; } v; v.f = f;
  uint32_t u = v.u;
  return (u16)((u + 0x7fffu + ((u >> 16) & 1u)) >> 16);
}
__device__ __forceinline__ float bf2f(u16 h) {
  union { uint32_t u; float f; } v; v.u = ((uint32_t)h) << 16;
  return v.f;
}
// one-instruction 2xf32 -> packed bf16 (RNE); compiler can't derive this from
// the manual-rounding f2bf, so inline asm is a real ~4x VALU saving per pair.
__device__ __forceinline__ uint32_t cvtpk(float lo, float hi_) {
  uint32_t r; asm("v_cvt_pk_bf16_f32 %0, %1, %2" : "=v"(r) : "v"(lo), "v"(hi_)); return r;
}
// raw v_exp_f32: computes 2^x (log2e pre-folded into Q scale)
__device__ __forceinline__ float exp2v(float x) {
  float r; asm("v_exp_f32 %0, %1" : "=v"(r) : "v"(x)); return r;
}

__device__ __forceinline__ void gl_lds16(const void* g, void* l) {
  __builtin_amdgcn_global_load_lds(
      (const __attribute__((address_space(1))) void*)g,
      (__attribute__((address_space(3))) void*)l, 16, 0, 0);
}

#define MFMA(a, b, c)  __builtin_amdgcn_mfma_f32_16x16x32_bf16((a), (b), (c), 0, 0, 0)
#define MFMA32(a, b, c) __builtin_amdgcn_mfma_f32_32x32x16_bf16((a), (b), (c), 0, 0, 0)
#define PLSWAP(x, y) asm volatile("v_permlane32_swap_b32 %0, %1" : "+v"(x), "+v"(y))

// ---------------- cast f32 -> bf16 ----------------
__global__ void cast_kernel(const float* __restrict__ in, u16* __restrict__ out, int n8) {
  int i = blockIdx.x * blockDim.x + threadIdx.x;
  if (i >= n8) return;
  const float4* p = (const float4*)in + (size_t)i * 2;
  float4 a = p[0], b = p[1];
  u16x8 r;
  r[0] = f2bf(a.x); r[1] = f2bf(a.y); r[2] = f2bf(a.z); r[3] = f2bf(a.w);
  r[4] = f2bf(b.x); r[5] = f2bf(b.y); r[6] = f2bf(b.z); r[7] = f2bf(b.w);
  *((u16x8*)out + i) = r;
}

// ---------------- GEMM-NT 128^2 (known-good; used for K/V proj) ----------------
template <bool OUT_F32>
__global__ __launch_bounds__(256, 2)
void gemm_bt(const u16* __restrict__ A, const u16* __restrict__ Bw,
             void* __restrict__ C, int M, int N, int K) {
  __shared__ u16 lA[128 * 32];
  __shared__ u16 lB[128 * 32];
  const int tid = threadIdx.x;
  const int w = tid >> 6, l = tid & 63;
  const int lc = l & 15, lg = l >> 4;
  const int bn = blockIdx.x, bm = blockIdx.y;
  const int wr = w >> 1, wc = w & 1;
  const u16* Ab = A + (size_t)(bm * 128) * K;
  const u16* Bb = Bw + (size_t)(bn * 128) * K;
  const int srow = l >> 2;
  const int scol = (l & 3) * 8;

  f32x4 acc[4][4];
#pragma unroll
  for (int i = 0; i < 4; ++i)
#pragma unroll
    for (int j = 0; j < 4; ++j) acc[i][j] = (f32x4){0.f, 0.f, 0.f, 0.f};

  const int nk = K >> 5;
  for (int kt = 0; kt < nk; ++kt) {
    const int k0 = kt * 32;
    __syncthreads();
#pragma unroll
    for (int i = 0; i < 2; ++i) {
      const int rowA = (w * 2 + i) * 16;
      gl_lds16(Ab + (size_t)(rowA + srow) * K + k0 + scol, &lA[rowA * 32]);
      gl_lds16(Bb + (size_t)(rowA + srow) * K + k0 + scol, &lB[rowA * 32]);
    }
    __syncthreads();
    bf16x8 af[4], bfr[4];
#pragma unroll
    for (int mi = 0; mi < 4; ++mi)
      af[mi] = *(const bf16x8*)&lA[(wr * 64 + mi * 16 + lc) * 32 + lg * 8];
#pragma unroll
    for (int ni = 0; ni < 4; ++ni)
      bfr[ni] = *(const bf16x8*)&lB[(wc * 64 + ni * 16 + lc) * 32 + lg * 8];
#pragma unroll
    for (int mi = 0; mi < 4; ++mi)
#pragma unroll
      for (int ni = 0; ni < 4; ++ni)
        acc[mi][ni] = MFMA(af[mi], bfr[ni], acc[mi][ni]);
  }

#pragma unroll
  for (int mi = 0; mi < 4; ++mi)
#pragma unroll
    for (int ni = 0; ni < 4; ++ni)
#pragma unroll
      for (int r = 0; r < 4; ++r) {
        const int row = bm * 128 + wr * 64 + mi * 16 + lg * 4 + r;
        const int col = bn * 128 + wc * 64 + ni * 16 + lc;
        if constexpr (OUT_F32)
          ((float*)C)[(size_t)row * N + col] = acc[mi][ni][r];
        else
          ((u16*)C)[(size_t)row * N + col] = f2bf(acc[mi][ni][r]);
      }
}

// ---------------- GEMM-NT 256^2, BK=64, 8 waves, 4-phase pipelined ------------
template <bool OUT_F32>
__global__ __launch_bounds__(512, 2)
void gemm256_bt(const u16* __restrict__ A, const u16* __restrict__ Bw,
                void* __restrict__ C, int M, int N, int K) {
  __shared__ u16 sA[2 * 256 * 64];
  __shared__ u16 sB[2 * 256 * 64];
  const int tid = threadIdx.x;
  const int w = tid >> 6, l = tid & 63;
  const int lc = l & 15, lg = l >> 4;
  const int wm = w >> 2, wn = w & 3;          // 2 x 4 wave grid
  const int nbn = N >> 8;
  const int nwg = (M >> 8) * nbn;
  const int cpx = nwg >> 3;
  const int lin = blockIdx.x;
  const int swz = (lin & 7) * cpx + (lin >> 3);
  const int bm = swz / nbn, bn = swz % nbn;
  const u16* Ab = A + (size_t)(bm * 256) * K;
  const u16* Bb = Bw + (size_t)(bn * 256) * K;
  const int lr = l >> 3;
  const int scc = ((l & 7) ^ lr) * 8;
  int cxg[2];
#pragma unroll
  for (int kk = 0; kk < 2; ++kk) cxg[kk] = ((kk * 4 + lg) ^ (lc & 7)) * 8;

  f32x4 acc[8][4];
#pragma unroll
  for (int i = 0; i < 8; ++i)
#pragma unroll
    for (int j = 0; j < 4; ++j) acc[i][j] = (f32x4){0.f, 0.f, 0.f, 0.f};

  auto STAGEA = [&](int buf, int t1, int h) {
    const int k0 = t1 * 64;
#pragma unroll
    for (int j = 0; j < 2; ++j) {
      const int r0 = h * 128 + w * 16 + j * 8;
      gl_lds16(Ab + (size_t)(r0 + lr) * K + k0 + scc, &sA[buf * 16384 + r0 * 64]);
    }
  };
  auto STAGEB = [&](int buf, int t1, int h) {
    const int k0 = t1 * 64;
#pragma unroll
    for (int j = 0; j < 2; ++j) {
      const int r0 = h * 128 + w * 16 + j * 8;
      gl_lds16(Bb + (size_t)(r0 + lr) * K + k0 + scc, &sB[buf * 16384 + r0 * 64]);
    }
  };

  STAGEA(0, 0, 0); STAGEA(0, 0, 1);
  STAGEB(0, 0, 0); STAGEB(0, 0, 1);
  asm volatile("s_waitcnt vmcnt(0)" ::: "memory");
  __builtin_amdgcn_s_barrier();
  asm volatile("" ::: "memory");

  const int nk = K >> 6;
  for (int t = 0; t < nk; ++t) {
    const int cur = t & 1;
    const int cb = cur * 16384;
    const bool pf = (t + 1 < nk);
#pragma unroll
    for (int p = 0; p < 4; ++p) {
      const int qm = p >> 1, qn = p & 1;
      bf16x8 af[4][2], bfr[2][2];
#pragma unroll
      for (int mi = 0; mi < 4; ++mi)
#pragma unroll
        for (int kk = 0; kk < 2; ++kk)
          af[mi][kk] = *(const bf16x8*)
              &sA[cb + (wm * 128 + qm * 64 + mi * 16 + lc) * 64 + cxg[kk]];
#pragma unroll
      for (int ni = 0; ni < 2; ++ni)
#pragma unroll
        for (int kk = 0; kk < 2; ++kk)
          bfr[ni][kk] = *(const bf16x8*)
              &sB[cb + (wn * 64 + qn * 32 + ni * 16 + lc) * 64 + cxg[kk]];
      if (pf) {
        if (p == 0) { STAGEA(cur ^ 1, t + 1, 0); STAGEA(cur ^ 1, t + 1, 1); }
        if (p == 1) { STAGEB(cur ^ 1, t + 1, 0); }
        if (p == 2) { STAGEB(cur ^ 1, t + 1, 1); }
      }
      __builtin_amdgcn_s_barrier();
      asm volatile("s_waitcnt lgkmcnt(0)" ::: "memory");
      __builtin_amdgcn_sched_barrier(0);
      __builtin_amdgcn_s_setprio(1);
#pragma unroll
      for (int kk = 0; kk < 2; ++kk)
#pragma unroll
        for (int mi = 0; mi < 4; ++mi)
#pragma unroll
          for (int ni = 0; ni < 2; ++ni)
            acc[qm * 4 + mi][qn * 2 + ni] =
                MFMA(af[mi][kk], bfr[ni][kk], acc[qm * 4 + mi][qn * 2 + ni]);
      __builtin_amdgcn_s_setprio(0);
      if (p == 3) asm volatile("s_waitcnt vmcnt(0)" ::: "memory");
      __builtin_amdgcn_s_barrier();
      asm volatile("" ::: "memory");
    }
  }

#pragma unroll
  for (int mi = 0; mi < 8; ++mi)
#pragma unroll
    for (int ni = 0; ni < 4; ++ni)
#pragma unroll
      for (int r = 0; r < 4; ++r) {
        const int row = bm * 256 + wm * 128 + mi * 16 + lg * 4 + r;
        const int col = bn * 256 + wn * 64 + ni * 16 + lc;
        if constexpr (OUT_F32)
          ((float*)C)[(size_t)row * N + col] = acc[mi][ni][r];
        else
          ((u16*)C)[(size_t)row * N + col] = f2bf(acc[mi][ni][r]);
      }
}

// ---------------- RoPE (scale folded into Q) ----------------
template <int NH>
__global__ void rope_kernel(const u16* __restrict__ lin, const float* __restrict__ fr,
                            u16* __restrict__ out, float scale) {
  int idx = blockIdx.x * 256 + threadIdx.x;
  const int total = B_ * S_ * NH * 64;
  if (idx >= total) return;
  const int i = idx & 63;
  const int h = (idx >> 6) % NH;
  const int t = idx / (64 * NH);
  const int s = t & (S_ - 1);
  const int b = t >> 11;
  const size_t src = (size_t)t * (NH * HD_) + h * HD_ + 2 * i;
  const float x0 = bf2f(lin[src]);
  const float x1 = bf2f(lin[src + 1]);
  const float2 cs = ((const float2*)fr)[s * 64 + i];
  const float o0 = (x0 * cs.x - x1 * cs.y) * scale;
  const float o1 = (x1 * cs.x + x0 * cs.y) * scale;
  const size_t dst = ((size_t)((b * NH + h) * S_ + s)) * HD_ + 2 * i;
  out[dst] = f2bf(o0);
  out[dst + 1] = f2bf(o1);
}

// ---------------- V transpose ----------------
__global__ void vtrans_kernel(const u16* __restrict__ vlin, u16* __restrict__ vt) {
  __shared__ u16 tile[32][33];
  const int tx = threadIdx.x, ty = threadIdx.y;  // (32, 8)
  const int s0 = blockIdx.x * 32;
  const int d0 = blockIdx.y * 32;
  const int bk = blockIdx.z;
  const int b = bk >> 3, kv = bk & 7;
#pragma unroll
  for (int r = 0; r < 4; ++r) {
    const int s = s0 + ty + r * 8;
    tile[ty + r * 8][tx] = vlin[((size_t)(b * S_ + s)) * (KVH_ * HD_) + kv * HD_ + d0 + tx];
  }
  __syncthreads();
#pragma unroll
  for (int r = 0; r < 4; ++r) {
    const int d = d0 + ty + r * 8;
    vt[((size_t)bk * HD_ + d) * S_ + s0 + tx] = tile[tx][ty + r * 8];
  }
}

// ---------------- causal GQA flash attention, 32x32 swapped-QK ----------------
// Scores arrive in log2 domain (log2e folded into Q scale): exp -> v_exp_f32,
// bf16 pack -> v_cvt_pk_bf16_f32, O-rescale deferred (THR=8 in log2 units).
__global__ __launch_bounds__(256, 2)
void attn_kernel(const u16* __restrict__ Q, const u16* __restrict__ K,
                 const u16* __restrict__ V, u16* __restrict__ O) {
  __shared__ u16 sK[2][64 * HD_];   // [key][d], 16B-chunk XOR-swizzled
  __shared__ u16 sV[2][HD_ * 64];   // [d][s],  16B-chunk XOR-swizzled
  const int tid = threadIdx.x;
  const int w = tid >> 6, l = tid & 63;
  const int hi = l >> 5, q32 = l & 31;
  const int qt = 63 - blockIdx.x;           // longest first
  const int kv = blockIdx.y, b = blockIdx.z;
  const int h = kv * 4 + w;
  const int qg = qt * 32 + q32;
  const u16* Qp = Q + ((size_t)(b * H_ + h) * S_ + qt * 32) * HD_;
  const u16* Kp = K + ((size_t)(b * KVH_ + kv) * S_) * HD_;
  const u16* Vp = V + ((size_t)(b * KVH_ + kv) * HD_) * S_;

  int koff[4], voff[4];
#pragma unroll
  for (int i = 0; i < 4; ++i) {
    const int kr = w * 16 + i * 4 + (l >> 4);
    koff[i] = kr * HD_ + (((l & 15) ^ (kr & 7))) * 8;
    const int vr = w * 32 + i * 8 + (l >> 3);
    voff[i] = vr * S_ + (((l & 7) ^ (vr & 7))) * 8;
  }
  int cx[8];
#pragma unroll
  for (int c = 0; c < 8; ++c) cx[c] = ((c * 2 + hi) ^ (l & 7)) * 8;

  bf16x8 qf[8];
#pragma unroll
  for (int ds = 0; ds < 8; ++ds)
    qf[ds] = *(const bf16x8*)(Qp + (size_t)q32 * HD_ + ds * 16 + hi * 8);
  asm volatile("s_waitcnt vmcnt(0)" ::: "memory");

  f32x16 out[4];
#pragma unroll
  for (int d = 0; d < 4; ++d)
#pragma unroll
    for (int r = 0; r < 16; ++r) out[d][r] = 0.f;
  float mrun = -1e30f, lrun = 0.f;

  auto STAGE = [&](int bufi, int ti) {
    const u16* kg = Kp + (size_t)ti * (64 * HD_);
    const u16* vg = Vp + (size_t)ti * 64;
#pragma unroll
    for (int i = 0; i < 4; ++i) {
      gl_lds16(kg + koff[i], &sK[bufi][(w * 16 + i * 4) * HD_]);
      gl_lds16(vg + voff[i], &sV[bufi][(w * 32 + i * 8) * 64]);
    }
  };

  const int nt = (qt >> 1) + 1;
  int cur = 0;
  STAGE(0, 0);

  for (int t = 0; t < nt; ++t) {
    if (t + 1 < nt) {
      STAGE(cur ^ 1, t + 1);
      asm volatile("s_waitcnt vmcnt(8)" ::: "memory");
    } else {
      asm volatile("s_waitcnt vmcnt(0)" ::: "memory");
    }
    __builtin_amdgcn_s_barrier();
    asm volatile("" ::: "memory");

    f32x16 sc0, sc1;
#pragma unroll
    for (int r = 0; r < 16; ++r) { sc0[r] = 0.f; sc1[r] = 0.f; }
    __builtin_amdgcn_s_setprio(1);
#pragma unroll
    for (int ds = 0; ds < 8; ++ds) {
      bf16x8 kf0 = *(const bf16x8*)&sK[cur][q32 * HD_ + cx[ds]];
      bf16x8 kf1 = *(const bf16x8*)&sK[cur][(32 + q32) * HD_ + cx[ds]];
      sc0 = MFMA32(kf0, qf[ds], sc0);
      sc1 = MFMA32(kf1, qf[ds], sc1);
    }
    __builtin_amdgcn_s_setprio(0);

    const bool diag = (t == nt - 1);
    float p0[16], p1[16];
#pragma unroll
    for (int r = 0; r < 16; ++r) {
      const int krow = (r & 3) + 8 * (r >> 2) + 4 * hi;
      float v0 = sc0[r], v1 = sc1[r];
      if (diag) {
        if (t * 64 + krow > qg) v0 = -1e9f;
        if (t * 64 + 32 + krow > qg) v1 = -1e9f;
      }
      p0[r] = v0; p1[r] = v1;
    }
    float rm = -1e30f;
#pragma unroll
    for (int r = 0; r < 16; ++r) rm = fmaxf(rm, fmaxf(p0[r], p1[r]));
    rm = fmaxf(rm, __shfl_xor(rm, 32, 64));
    // defer-max: skip O/l rescale while tile max stays within 2^8 of running max
    if (!__all(rm <= mrun + 8.0f)) {
      const float mnew = fmaxf(mrun, rm);
      const float alpha = exp2v(mrun - mnew);
      mrun = mnew;
      lrun *= alpha;
#pragma unroll
      for (int d = 0; d < 4; ++d) out[d] *= alpha;
    }
    float sum = 0.f;
#pragma unroll
    for (int r = 0; r < 16; ++r) {
      p0[r] = exp2v(p0[r] - mrun);
      p1[r] = exp2v(p1[r] - mrun);
      sum += p0[r] + p1[r];
    }
    sum += __shfl_xor(sum, 32, 64);
    lrun += sum;
    uint32_t pk0[8], pk1[8];
#pragma unroll
    for (int g = 0; g < 4; ++g) {
      pk0[2 * g]     = cvtpk(p0[4 * g], p0[4 * g + 1]);
      pk0[2 * g + 1] = cvtpk(p0[4 * g + 2], p0[4 * g + 3]);
      pk1[2 * g]     = cvtpk(p1[4 * g], p1[4 * g + 1]);
      pk1[2 * g + 1] = cvtpk(p1[4 * g + 2], p1[4 * g + 3]);
    }
    PLSWAP(pk0[0], pk0[2]); PLSWAP(pk0[1], pk0[3]);
    PLSWAP(pk0[4], pk0[6]); PLSWAP(pk0[5], pk0[7]);
    PLSWAP(pk1[0], pk1[2]); PLSWAP(pk1[1], pk1[3]);
    PLSWAP(pk1[4], pk1[6]); PLSWAP(pk1[5], pk1[7]);
    bf16x8 pa[4];
    pa[0] = __builtin_bit_cast(bf16x8, (u32x4){pk0[0], pk0[1], pk0[2], pk0[3]});
    pa[1] = __builtin_bit_cast(bf16x8, (u32x4){pk0[4], pk0[5], pk0[6], pk0[7]});
    pa[2] = __builtin_bit_cast(bf16x8, (u32x4){pk1[0], pk1[1], pk1[2], pk1[3]});
    pa[3] = __builtin_bit_cast(bf16x8, (u32x4){pk1[4], pk1[5], pk1[6], pk1[7]});
    __builtin_amdgcn_s_setprio(1);
#pragma unroll
    for (int d = 0; d < 4; ++d) {
      const int vbase = (d * 32 + q32) * 64;
#pragma unroll
      for (int kk = 0; kk < 4; ++kk) {
        bf16x8 vf = *(const bf16x8*)&sV[cur][vbase + cx[kk]];
        out[d] = MFMA32(vf, pa[kk], out[d]);
      }
    }
    __builtin_amdgcn_s_setprio(0);
    asm volatile("" ::: "memory");
    __builtin_amdgcn_s_barrier();
    cur ^= 1;
  }

  const float inv = 1.0f / lrun;
  u16* myS = ((u16*)sK) + w * 4096;
#pragma unroll
  for (int d = 0; d < 4; ++d)
#pragma unroll
    for (int rq = 0; rq < 4; ++rq) {
      u32x2 pw;
      pw[0] = cvtpk(out[d][rq * 4 + 0] * inv, out[d][rq * 4 + 1] * inv);
      pw[1] = cvtpk(out[d][rq * 4 + 2] * inv, out[d][rq * 4 + 3] * inv);
      const int gin = (d * 8 + rq * 2 + hi) ^ (q32 & 15);
      *(u32x2*)&myS[q32 * 128 + gin * 4] = pw;
    }
  asm volatile("s_waitcnt lgkmcnt(0)" ::: "memory");
  __builtin_amdgcn_sched_barrier(0);
  const int rr = l >> 4;
  const int cc = l & 15;
#pragma unroll
  for (int p = 0; p < 8; ++p) {
    const int q = p * 4 + rr;
    const int ga = (2 * cc) ^ (q & 15);
    const int gb = (2 * cc + 1) ^ (q & 15);
    u32x2 va = *(const u32x2*)&myS[q * 128 + ga * 4];
    u32x2 vb = *(const u32x2*)&myS[q * 128 + gb * 4];
    u32x4 val = {va[0], va[1], vb[0], vb[1]};
    *(u32x4*)&O[((size_t)(b * S_ + qt * 32 + q)) * (H_ * HD_) + h * HD_ + cc * 8] = val;
  }
}

// ---------------- launch ----------------
extern "C" void kernel_launch(void* const* d_in, const int* in_sizes, int n_in,
                              void* d_out, int out_size, void* d_ws, size_t ws_size,
                              hipStream_t stream) {
  const float* x     = (const float*)d_in[0];
  const float* freqs = (const float*)d_in[2];
  const float* wq    = (const float*)d_in[4];
  const float* wk    = (const float*)d_in[5];
  const float* wv    = (const float*)d_in[6];
  const float* wo    = (const float*)d_in[7];

  char* ws = (char*)d_ws;
  u16* xb   = (u16*)(ws + 0);
  u16* wqb  = (u16*)(ws + 33554432);
  u16* wkb  = (u16*)(ws + 67108864);
  u16* wvb  = (u16*)(ws + 75497472);
  u16* qlin = (u16*)(ws + 83886080);
  u16* klin = (u16*)(ws + 117440512);
  u16* vlin = (u16*)(ws + 125829120);
  u16* qr   = wqb;   // rope'd Q (pre-scaled by log2e/sqrt(128))
  u16* kr   = wkb;   // rope'd K
  u16* vt   = wvb;   // V^T
  u16* aout = qlin;  // attention output
  u16* wob  = xb;    // bf16 wo

  cast_kernel<<<8192, 256, 0, stream>>>(x, xb, 2097152);
  cast_kernel<<<8192, 256, 0, stream>>>(wq, wqb, 2097152);
  cast_kernel<<<2048, 256, 0, stream>>>(wk, wkb, 524288);
  cast_kernel<<<2048, 256, 0, stream>>>(wv, wvb, 524288);
  gemm256_bt<false><<<256, 512, 0, stream>>>(xb, wqb, qlin, 4096, 4096, 4096);
  gemm_bt<false><<<dim3(8, 32), 256, 0, stream>>>(xb, wkb, klin, 4096, 1024, 4096);
  gemm_bt<false><<<dim3(8, 32), 256, 0, stream>>>(xb, wvb, vlin, 4096, 1024, 4096);
  rope_kernel<32><<<32768, 256, 0, stream>>>(qlin, freqs, qr,
      0.08838834764831845f * 1.4426950408889634f);  // 1/sqrt(128) * log2(e)
  rope_kernel<8><<<8192, 256, 0, stream>>>(klin, freqs, kr, 1.0f);
  vtrans_kernel<<<dim3(64, 4, 16), dim3(32, 8), 0, stream>>>(vlin, vt);
  attn_kernel<<<dim3(64, 8, 2), 256, 0, stream>>>(qr, kr, vt, aout);
  cast_kernel<<<8192, 256, 0, stream>>>(wo, wob, 2097152);
  gemm256_bt<true><<<256, 512, 0, stream>>>(aout, wob, d_out, 4096, 4096, 4096);
}

// Round 8
// 611.420 us; speedup vs baseline: 1.6070x; 1.1065x over previous
//
#include <hip/hip_runtime.h>
#include <cstdint>
#include <cstddef>

#define B_   2
#define S_   2048
#define D_   4096
#define H_   32
#define KVH_ 8
#define HD_  128

typedef unsigned short u16;
typedef short     bf16x8 __attribute__((ext_vector_type(8)));
typedef float     f32x4  __attribute__((ext_vector_type(4)));
typedef float     f32x16 __attribute__((ext_vector_type(16)));
typedef u16       u16x8  __attribute__((ext_vector_type(8)));
typedef uint32_t  u32x2  __attribute__((ext_vector_type(2)));
typedef uint32_t  u32x4  __attribute__((ext_vector_type(4)));

__device__ __forceinline__ u16 f2bf(float f) {
  union { float f; uint32_t u; } v; v.f = f;
  uint32_t u = v.u;
  return (u16)((u + 0x7fffu + ((u >> 16) & 1u)) >> 16);
}
__device__ __forceinline__ float bf2f(u16 h) {
  union { uint32_t u; float f; } v; v.u = ((uint32_t)h) << 16;
  return v.f;
}
__device__ __forceinline__ uint32_t cvtpk(float lo, float hi_) {
  uint32_t r; asm("v_cvt_pk_bf16_f32 %0, %1, %2" : "=v"(r) : "v"(lo), "v"(hi_)); return r;
}
__device__ __forceinline__ float exp2v(float x) {
  float r; asm("v_exp_f32 %0, %1" : "=v"(r) : "v"(x)); return r;
}

__device__ __forceinline__ void gl_lds16(const void* g, void* l) {
  __builtin_amdgcn_global_load_lds(
      (const __attribute__((address_space(1))) void*)g,
      (__attribute__((address_space(3))) void*)l, 16, 0, 0);
}

#define MFMA(a, b, c)  __builtin_amdgcn_mfma_f32_16x16x32_bf16((a), (b), (c), 0, 0, 0)
#define MFMA32(a, b, c) __builtin_amdgcn_mfma_f32_32x32x16_bf16((a), (b), (c), 0, 0, 0)
#define PLSWAP(x, y) asm volatile("v_permlane32_swap_b32 %0, %1" : "+v"(x), "+v"(y))

// ---------------- cast f32 -> bf16 ----------------
__global__ void cast_kernel(const float* __restrict__ in, u16* __restrict__ out, int n8) {
  int i = blockIdx.x * blockDim.x + threadIdx.x;
  if (i >= n8) return;
  const float4* p = (const float4*)in + (size_t)i * 2;
  float4 a = p[0], b = p[1];
  u16x8 r;
  r[0] = f2bf(a.x); r[1] = f2bf(a.y); r[2] = f2bf(a.z); r[3] = f2bf(a.w);
  r[4] = f2bf(b.x); r[5] = f2bf(b.y); r[6] = f2bf(b.z); r[7] = f2bf(b.w);
  *((u16x8*)out + i) = r;
}

// ---------------- GEMM-NT 128^2 (known-good; used for K/V proj) ----------------
template <bool OUT_F32>
__global__ __launch_bounds__(256, 2)
void gemm_bt(const u16* __restrict__ A, const u16* __restrict__ Bw,
             void* __restrict__ C, int M, int N, int K) {
  __shared__ u16 lA[128 * 32];
  __shared__ u16 lB[128 * 32];
  const int tid = threadIdx.x;
  const int w = tid >> 6, l = tid & 63;
  const int lc = l & 15, lg = l >> 4;
  const int bn = blockIdx.x, bm = blockIdx.y;
  const int wr = w >> 1, wc = w & 1;
  const u16* Ab = A + (size_t)(bm * 128) * K;
  const u16* Bb = Bw + (size_t)(bn * 128) * K;
  const int srow = l >> 2;
  const int scol = (l & 3) * 8;

  f32x4 acc[4][4];
#pragma unroll
  for (int i = 0; i < 4; ++i)
#pragma unroll
    for (int j = 0; j < 4; ++j) acc[i][j] = (f32x4){0.f, 0.f, 0.f, 0.f};

  const int nk = K >> 5;
  for (int kt = 0; kt < nk; ++kt) {
    const int k0 = kt * 32;
    __syncthreads();
#pragma unroll
    for (int i = 0; i < 2; ++i) {
      const int rowA = (w * 2 + i) * 16;
      gl_lds16(Ab + (size_t)(rowA + srow) * K + k0 + scol, &lA[rowA * 32]);
      gl_lds16(Bb + (size_t)(rowA + srow) * K + k0 + scol, &lB[rowA * 32]);
    }
    __syncthreads();
    bf16x8 af[4], bfr[4];
#pragma unroll
    for (int mi = 0; mi < 4; ++mi)
      af[mi] = *(const bf16x8*)&lA[(wr * 64 + mi * 16 + lc) * 32 + lg * 8];
#pragma unroll
    for (int ni = 0; ni < 4; ++ni)
      bfr[ni] = *(const bf16x8*)&lB[(wc * 64 + ni * 16 + lc) * 32 + lg * 8];
#pragma unroll
    for (int mi = 0; mi < 4; ++mi)
#pragma unroll
      for (int ni = 0; ni < 4; ++ni)
        acc[mi][ni] = MFMA(af[mi], bfr[ni], acc[mi][ni]);
  }

#pragma unroll
  for (int mi = 0; mi < 4; ++mi)
#pragma unroll
    for (int ni = 0; ni < 4; ++ni)
#pragma unroll
      for (int r = 0; r < 4; ++r) {
        const int row = bm * 128 + wr * 64 + mi * 16 + lg * 4 + r;
        const int col = bn * 128 + wc * 64 + ni * 16 + lc;
        if constexpr (OUT_F32)
          ((float*)C)[(size_t)row * N + col] = acc[mi][ni][r];
        else
          ((u16*)C)[(size_t)row * N + col] = f2bf(acc[mi][ni][r]);
      }
}

// ---------------- GEMM-NT 256^2, BK=64, 8 waves, 4-phase pipelined ------------
template <bool OUT_F32>
__global__ __launch_bounds__(512, 2)
void gemm256_bt(const u16* __restrict__ A, const u16* __restrict__ Bw,
                void* __restrict__ C, int M, int N, int K) {
  __shared__ u16 sA[2 * 256 * 64];
  __shared__ u16 sB[2 * 256 * 64];
  const int tid = threadIdx.x;
  const int w = tid >> 6, l = tid & 63;
  const int lc = l & 15, lg = l >> 4;
  const int wm = w >> 2, wn = w & 3;          // 2 x 4 wave grid
  const int nbn = N >> 8;
  const int nwg = (M >> 8) * nbn;
  const int cpx = nwg >> 3;
  const int lin = blockIdx.x;
  const int swz = (lin & 7) * cpx + (lin >> 3);
  const int bm = swz / nbn, bn = swz % nbn;
  const u16* Ab = A + (size_t)(bm * 256) * K;
  const u16* Bb = Bw + (size_t)(bn * 256) * K;
  const int lr = l >> 3;
  const int scc = ((l & 7) ^ lr) * 8;
  int cxg[2];
#pragma unroll
  for (int kk = 0; kk < 2; ++kk) cxg[kk] = ((kk * 4 + lg) ^ (lc & 7)) * 8;

  f32x4 acc[8][4];
#pragma unroll
  for (int i = 0; i < 8; ++i)
#pragma unroll
    for (int j = 0; j < 4; ++j) acc[i][j] = (f32x4){0.f, 0.f, 0.f, 0.f};

  auto STAGEA = [&](int buf, int t1, int h) {
    const int k0 = t1 * 64;
#pragma unroll
    for (int j = 0; j < 2; ++j) {
      const int r0 = h * 128 + w * 16 + j * 8;
      gl_lds16(Ab + (size_t)(r0 + lr) * K + k0 + scc, &sA[buf * 16384 + r0 * 64]);
    }
  };
  auto STAGEB = [&](int buf, int t1, int h) {
    const int k0 = t1 * 64;
#pragma unroll
    for (int j = 0; j < 2; ++j) {
      const int r0 = h * 128 + w * 16 + j * 8;
      gl_lds16(Bb + (size_t)(r0 + lr) * K + k0 + scc, &sB[buf * 16384 + r0 * 64]);
    }
  };

  STAGEA(0, 0, 0); STAGEA(0, 0, 1);
  STAGEB(0, 0, 0); STAGEB(0, 0, 1);
  asm volatile("s_waitcnt vmcnt(0)" ::: "memory");
  __builtin_amdgcn_s_barrier();
  asm volatile("" ::: "memory");

  const int nk = K >> 6;
  for (int t = 0; t < nk; ++t) {
    const int cur = t & 1;
    const int cb = cur * 16384;
    const bool pf = (t + 1 < nk);
#pragma unroll
    for (int p = 0; p < 4; ++p) {
      const int qm = p >> 1, qn = p & 1;
      bf16x8 af[4][2], bfr[2][2];
#pragma unroll
      for (int mi = 0; mi < 4; ++mi)
#pragma unroll
        for (int kk = 0; kk < 2; ++kk)
          af[mi][kk] = *(const bf16x8*)
              &sA[cb + (wm * 128 + qm * 64 + mi * 16 + lc) * 64 + cxg[kk]];
#pragma unroll
      for (int ni = 0; ni < 2; ++ni)
#pragma unroll
        for (int kk = 0; kk < 2; ++kk)
          bfr[ni][kk] = *(const bf16x8*)
              &sB[cb + (wn * 64 + qn * 32 + ni * 16 + lc) * 64 + cxg[kk]];
      if (pf) {
        if (p == 0) { STAGEA(cur ^ 1, t + 1, 0); STAGEA(cur ^ 1, t + 1, 1); }
        if (p == 1) { STAGEB(cur ^ 1, t + 1, 0); }
        if (p == 2) { STAGEB(cur ^ 1, t + 1, 1); }
      }
      __builtin_amdgcn_s_barrier();
      asm volatile("s_waitcnt lgkmcnt(0)" ::: "memory");
      __builtin_amdgcn_sched_barrier(0);
      __builtin_amdgcn_s_setprio(1);
#pragma unroll
      for (int kk = 0; kk < 2; ++kk)
#pragma unroll
        for (int mi = 0; mi < 4; ++mi)
#pragma unroll
          for (int ni = 0; ni < 2; ++ni)
            acc[qm * 4 + mi][qn * 2 + ni] =
                MFMA(af[mi][kk], bfr[ni][kk], acc[qm * 4 + mi][qn * 2 + ni]);
      __builtin_amdgcn_s_setprio(0);
      if (p == 3) asm volatile("s_waitcnt vmcnt(0)" ::: "memory");
      __builtin_amdgcn_s_barrier();
      asm volatile("" ::: "memory");
    }
  }

#pragma unroll
  for (int mi = 0; mi < 8; ++mi)
#pragma unroll
    for (int ni = 0; ni < 4; ++ni)
#pragma unroll
      for (int r = 0; r < 4; ++r) {
        const int row = bm * 256 + wm * 128 + mi * 16 + lg * 4 + r;
        const int col = bn * 256 + wn * 64 + ni * 16 + lc;
        if constexpr (OUT_F32)
          ((float*)C)[(size_t)row * N + col] = acc[mi][ni][r];
        else
          ((u16*)C)[(size_t)row * N + col] = f2bf(acc[mi][ni][r]);
      }
}

// ---------------- RoPE (scale folded into Q) ----------------
template <int NH>
__global__ void rope_kernel(const u16* __restrict__ lin, const float* __restrict__ fr,
                            u16* __restrict__ out, float scale) {
  int idx = blockIdx.x * 256 + threadIdx.x;
  const int total = B_ * S_ * NH * 64;
  if (idx >= total) return;
  const int i = idx & 63;
  const int h = (idx >> 6) % NH;
  const int t = idx / (64 * NH);
  const int s = t & (S_ - 1);
  const int b = t >> 11;
  const size_t src = (size_t)t * (NH * HD_) + h * HD_ + 2 * i;
  const float x0 = bf2f(lin[src]);
  const float x1 = bf2f(lin[src + 1]);
  const float2 cs = ((const float2*)fr)[s * 64 + i];
  const float o0 = (x0 * cs.x - x1 * cs.y) * scale;
  const float o1 = (x1 * cs.x + x0 * cs.y) * scale;
  const size_t dst = ((size_t)((b * NH + h) * S_ + s)) * HD_ + 2 * i;
  out[dst] = f2bf(o0);
  out[dst + 1] = f2bf(o1);
}

// ---------------- V transpose ----------------
__global__ void vtrans_kernel(const u16* __restrict__ vlin, u16* __restrict__ vt) {
  __shared__ u16 tile[32][33];
  const int tx = threadIdx.x, ty = threadIdx.y;  // (32, 8)
  const int s0 = blockIdx.x * 32;
  const int d0 = blockIdx.y * 32;
  const int bk = blockIdx.z;
  const int b = bk >> 3, kv = bk & 7;
#pragma unroll
  for (int r = 0; r < 4; ++r) {
    const int s = s0 + ty + r * 8;
    tile[ty + r * 8][tx] = vlin[((size_t)(b * S_ + s)) * (KVH_ * HD_) + kv * HD_ + d0 + tx];
  }
  __syncthreads();
#pragma unroll
  for (int r = 0; r < 4; ++r) {
    const int d = d0 + ty + r * 8;
    vt[((size_t)bk * HD_ + d) * S_ + s0 + tx] = tile[tx][ty + r * 8];
  }
}

// ---------------- causal GQA flash attention, 32x32 swapped-QK ----------------
// Two complementary q-tiles per block (qt = bx and 63-bx): uniform ~33 key-tiles
// per block. Grid 512 blocks x 4 waves = exactly 2 blocks/CU, zero imbalance.
__global__ __launch_bounds__(256, 2)
void attn_kernel(const u16* __restrict__ Q, const u16* __restrict__ K,
                 const u16* __restrict__ V, u16* __restrict__ O) {
  __shared__ u16 sK[2][64 * HD_];   // [key][d], 16B-chunk XOR-swizzled
  __shared__ u16 sV[2][HD_ * 64];   // [d][s],  16B-chunk XOR-swizzled
  const int tid = threadIdx.x;
  const int w = tid >> 6, l = tid & 63;
  const int hi = l >> 5, q32 = l & 31;
  const int kv = blockIdx.y, b = blockIdx.z;
  const int h = kv * 4 + w;
  const u16* Kp = K + ((size_t)(b * KVH_ + kv) * S_) * HD_;
  const u16* Vp = V + ((size_t)(b * KVH_ + kv) * HD_) * S_;

  int koff[4], voff[4];
#pragma unroll
  for (int i = 0; i < 4; ++i) {
    const int kr = w * 16 + i * 4 + (l >> 4);
    koff[i] = kr * HD_ + (((l & 15) ^ (kr & 7))) * 8;
    const int vr = w * 32 + i * 8 + (l >> 3);
    voff[i] = vr * S_ + (((l & 7) ^ (vr & 7))) * 8;
  }
  int cx[8];
#pragma unroll
  for (int c = 0; c < 8; ++c) cx[c] = ((c * 2 + hi) ^ (l & 7)) * 8;

  auto STAGE = [&](int bufi, int ti) {
    const u16* kg = Kp + (size_t)ti * (64 * HD_);
    const u16* vg = Vp + (size_t)ti * 64;
#pragma unroll
    for (int i = 0; i < 4; ++i) {
      gl_lds16(kg + koff[i], &sK[bufi][(w * 16 + i * 4) * HD_]);
      gl_lds16(vg + voff[i], &sV[bufi][(w * 32 + i * 8) * 64]);
    }
  };

  int cur = 0;
  for (int seg = 0; seg < 2; ++seg) {
    const int qt = seg ? (63 - blockIdx.x) : blockIdx.x;
    const int qg = qt * 32 + q32;
    const u16* Qp = Q + ((size_t)(b * H_ + h) * S_ + qt * 32) * HD_;

    bf16x8 qf[8];
#pragma unroll
    for (int ds = 0; ds < 8; ++ds)
      qf[ds] = *(const bf16x8*)(Qp + (size_t)q32 * HD_ + ds * 16 + hi * 8);
    asm volatile("s_waitcnt vmcnt(0)" ::: "memory");

    f32x16 out[4];
#pragma unroll
    for (int d = 0; d < 4; ++d)
#pragma unroll
      for (int r = 0; r < 16; ++r) out[d][r] = 0.f;
    float mrun = -1e30f, lrun = 0.f;

    const int nt = (qt >> 1) + 1;
    STAGE(cur, 0);

    for (int t = 0; t < nt; ++t) {
      if (t + 1 < nt) {
        STAGE(cur ^ 1, t + 1);
        asm volatile("s_waitcnt vmcnt(8)" ::: "memory");
      } else {
        asm volatile("s_waitcnt vmcnt(0)" ::: "memory");
      }
      __builtin_amdgcn_s_barrier();
      asm volatile("" ::: "memory");

      f32x16 sc0, sc1;
#pragma unroll
      for (int r = 0; r < 16; ++r) { sc0[r] = 0.f; sc1[r] = 0.f; }
      __builtin_amdgcn_s_setprio(1);
#pragma unroll
      for (int ds = 0; ds < 8; ++ds) {
        bf16x8 kf0 = *(const bf16x8*)&sK[cur][q32 * HD_ + cx[ds]];
        bf16x8 kf1 = *(const bf16x8*)&sK[cur][(32 + q32) * HD_ + cx[ds]];
        sc0 = MFMA32(kf0, qf[ds], sc0);
        sc1 = MFMA32(kf1, qf[ds], sc1);
      }
      __builtin_amdgcn_s_setprio(0);

      const bool diag = (t == nt - 1);
      float p0[16], p1[16];
#pragma unroll
      for (int r = 0; r < 16; ++r) {
        const int krow = (r & 3) + 8 * (r >> 2) + 4 * hi;
        float v0 = sc0[r], v1 = sc1[r];
        if (diag) {
          if (t * 64 + krow > qg) v0 = -1e9f;
          if (t * 64 + 32 + krow > qg) v1 = -1e9f;
        }
        p0[r] = v0; p1[r] = v1;
      }
      float rm = -1e30f;
#pragma unroll
      for (int r = 0; r < 16; ++r) rm = fmaxf(rm, fmaxf(p0[r], p1[r]));
      rm = fmaxf(rm, __shfl_xor(rm, 32, 64));
      if (!__all(rm <= mrun + 8.0f)) {
        const float mnew = fmaxf(mrun, rm);
        const float alpha = exp2v(mrun - mnew);
        mrun = mnew;
        lrun *= alpha;
#pragma unroll
        for (int d = 0; d < 4; ++d) out[d] *= alpha;
      }
      float sum = 0.f;
#pragma unroll
      for (int r = 0; r < 16; ++r) {
        p0[r] = exp2v(p0[r] - mrun);
        p1[r] = exp2v(p1[r] - mrun);
        sum += p0[r] + p1[r];
      }
      sum += __shfl_xor(sum, 32, 64);
      lrun += sum;
      uint32_t pk0[8], pk1[8];
#pragma unroll
      for (int g = 0; g < 4; ++g) {
        pk0[2 * g]     = cvtpk(p0[4 * g], p0[4 * g + 1]);
        pk0[2 * g + 1] = cvtpk(p0[4 * g + 2], p0[4 * g + 3]);
        pk1[2 * g]     = cvtpk(p1[4 * g], p1[4 * g + 1]);
        pk1[2 * g + 1] = cvtpk(p1[4 * g + 2], p1[4 * g + 3]);
      }
      PLSWAP(pk0[0], pk0[2]); PLSWAP(pk0[1], pk0[3]);
      PLSWAP(pk0[4], pk0[6]); PLSWAP(pk0[5], pk0[7]);
      PLSWAP(pk1[0], pk1[2]); PLSWAP(pk1[1], pk1[3]);
      PLSWAP(pk1[4], pk1[6]); PLSWAP(pk1[5], pk1[7]);
      bf16x8 pa[4];
      pa[0] = __builtin_bit_cast(bf16x8, (u32x4){pk0[0], pk0[1], pk0[2], pk0[3]});
      pa[1] = __builtin_bit_cast(bf16x8, (u32x4){pk0[4], pk0[5], pk0[6], pk0[7]});
      pa[2] = __builtin_bit_cast(bf16x8, (u32x4){pk1[0], pk1[1], pk1[2], pk1[3]});
      pa[3] = __builtin_bit_cast(bf16x8, (u32x4){pk1[4], pk1[5], pk1[6], pk1[7]});
      __builtin_amdgcn_s_setprio(1);
#pragma unroll
      for (int d = 0; d < 4; ++d) {
        const int vbase = (d * 32 + q32) * 64;
#pragma unroll
        for (int kk = 0; kk < 4; ++kk) {
          bf16x8 vf = *(const bf16x8*)&sV[cur][vbase + cx[kk]];
          out[d] = MFMA32(vf, pa[kk], out[d]);
        }
      }
      __builtin_amdgcn_s_setprio(0);
      asm volatile("" ::: "memory");
      __builtin_amdgcn_s_barrier();
      cur ^= 1;
    }

    // ---- epilogue: stage O tile through (now-free) sK for coalesced stores
    const float inv = 1.0f / lrun;
    u16* myS = ((u16*)sK) + w * 4096;
#pragma unroll
    for (int d = 0; d < 4; ++d)
#pragma unroll
      for (int rq = 0; rq < 4; ++rq) {
        u32x2 pw;
        pw[0] = cvtpk(out[d][rq * 4 + 0] * inv, out[d][rq * 4 + 1] * inv);
        pw[1] = cvtpk(out[d][rq * 4 + 2] * inv, out[d][rq * 4 + 3] * inv);
        const int gin = (d * 8 + rq * 2 + hi) ^ (q32 & 15);
        *(u32x2*)&myS[q32 * 128 + gin * 4] = pw;
      }
    asm volatile("s_waitcnt lgkmcnt(0)" ::: "memory");
    __builtin_amdgcn_sched_barrier(0);
    const int rr = l >> 4;
    const int cc = l & 15;
#pragma unroll
    for (int p = 0; p < 8; ++p) {
      const int q = p * 4 + rr;
      const int ga = (2 * cc) ^ (q & 15);
      const int gb = (2 * cc + 1) ^ (q & 15);
      u32x2 va = *(const u32x2*)&myS[q * 128 + ga * 4];
      u32x2 vb = *(const u32x2*)&myS[q * 128 + gb * 4];
      u32x4 val = {va[0], va[1], vb[0], vb[1]};
      *(u32x4*)&O[((size_t)(b * S_ + qt * 32 + q)) * (H_ * HD_) + h * HD_ + cc * 8] = val;
    }
    // protect myS (in sK) from next segment's staging writes
    if (seg == 0) {
      asm volatile("" ::: "memory");
      __builtin_amdgcn_s_barrier();
    }
  }
}

// ---------------- launch ----------------
extern "C" void kernel_launch(void* const* d_in, const int* in_sizes, int n_in,
                              void* d_out, int out_size, void* d_ws, size_t ws_size,
                              hipStream_t stream) {
  const float* x     = (const float*)d_in[0];
  const float* freqs = (const float*)d_in[2];
  const float* wq    = (const float*)d_in[4];
  const float* wk    = (const float*)d_in[5];
  const float* wv    = (const float*)d_in[6];
  const float* wo    = (const float*)d_in[7];

  char* ws = (char*)d_ws;
  u16* xb   = (u16*)(ws + 0);
  u16* wqb  = (u16*)(ws + 33554432);
  u16* wkb  = (u16*)(ws + 67108864);
  u16* wvb  = (u16*)(ws + 75497472);
  u16* qlin = (u16*)(ws + 83886080);
  u16* klin = (u16*)(ws + 117440512);
  u16* vlin = (u16*)(ws + 125829120);
  u16* qr   = wqb;   // rope'd Q (pre-scaled by log2e/sqrt(128))
  u16* kr   = wkb;   // rope'd K
  u16* vt   = wvb;   // V^T
  u16* aout = qlin;  // attention output
  u16* wob  = xb;    // bf16 wo

  cast_kernel<<<8192, 256, 0, stream>>>(x, xb, 2097152);
  cast_kernel<<<8192, 256, 0, stream>>>(wq, wqb, 2097152);
  cast_kernel<<<2048, 256, 0, stream>>>(wk, wkb, 524288);
  cast_kernel<<<2048, 256, 0, stream>>>(wv, wvb, 524288);
  gemm256_bt<false><<<256, 512, 0, stream>>>(xb, wqb, qlin, 4096, 4096, 4096);
  gemm_bt<false><<<dim3(8, 32), 256, 0, stream>>>(xb, wkb, klin, 4096, 1024, 4096);
  gemm_bt<false><<<dim3(8, 32), 256, 0, stream>>>(xb, wvb, vlin, 4096, 1024, 4096);
  rope_kernel<32><<<32768, 256, 0, stream>>>(qlin, freqs, qr,
      0.08838834764831845f * 1.4426950408889634f);  // 1/sqrt(128) * log2(e)
  rope_kernel<8><<<8192, 256, 0, stream>>>(klin, freqs, kr, 1.0f);
  vtrans_kernel<<<dim3(64, 4, 16), dim3(32, 8), 0, stream>>>(vlin, vt);
  attn_kernel<<<dim3(32, 8, 2), 256, 0, stream>>>(qr, kr, vt, aout);
  cast_kernel<<<8192, 256, 0, stream>>>(wo, wob, 2097152);
  gemm256_bt<true><<<256, 512, 0, stream>>>(aout, wob, d_out, 4096, 4096, 4096);
}

// Round 9
// 572.568 us; speedup vs baseline: 1.7161x; 1.0679x over previous
//
#include <hip/hip_runtime.h>
#include <cstdint>
#include <cstddef>

#define B_   2
#define S_   2048
#define D_   4096
#define H_   32
#define KVH_ 8
#define HD_  128

typedef unsigned short u16;
typedef short     bf16x8 __attribute__((ext_vector_type(8)));
typedef float     f32x4  __attribute__((ext_vector_type(4)));
typedef float     f32x16 __attribute__((ext_vector_type(16)));
typedef u16       u16x8  __attribute__((ext_vector_type(8)));
typedef uint32_t  u32x2  __attribute__((ext_vector_type(2)));
typedef uint32_t  u32x4  __attribute__((ext_vector_type(4)));

__device__ __forceinline__ u16 f2bf(float f) {
  union { float f; uint32_t u; } v; v.f = f;
  uint32_t u = v.u;
  return (u16)((u + 0x7fffu + ((u >> 16) & 1u)) >> 16);
}
__device__ __forceinline__ float bf2f(u16 h) {
  union { uint32_t u; float f; } v; v.u = ((uint32_t)h) << 16;
  return v.f;
}
__device__ __forceinline__ uint32_t cvtpk(float lo, float hi_) {
  uint32_t r; asm("v_cvt_pk_bf16_f32 %0, %1, %2" : "=v"(r) : "v"(lo), "v"(hi_)); return r;
}
__device__ __forceinline__ float exp2v(float x) {
  float r; asm("v_exp_f32 %0, %1" : "=v"(r) : "v"(x)); return r;
}

__device__ __forceinline__ void gl_lds16(const void* g, void* l) {
  __builtin_amdgcn_global_load_lds(
      (const __attribute__((address_space(1))) void*)g,
      (__attribute__((address_space(3))) void*)l, 16, 0, 0);
}

#define MFMA(a, b, c)  __builtin_amdgcn_mfma_f32_16x16x32_bf16((a), (b), (c), 0, 0, 0)
#define MFMA32(a, b, c) __builtin_amdgcn_mfma_f32_32x32x16_bf16((a), (b), (c), 0, 0, 0)
#define PLSWAP(x, y) asm volatile("v_permlane32_swap_b32 %0, %1" : "+v"(x), "+v"(y))

// ---------------- cast f32 -> bf16 ----------------
__global__ void cast_kernel(const float* __restrict__ in, u16* __restrict__ out, int n8) {
  int i = blockIdx.x * blockDim.x + threadIdx.x;
  if (i >= n8) return;
  const float4* p = (const float4*)in + (size_t)i * 2;
  float4 a = p[0], b = p[1];
  u16x8 r;
  r[0] = f2bf(a.x); r[1] = f2bf(a.y); r[2] = f2bf(a.z); r[3] = f2bf(a.w);
  r[4] = f2bf(b.x); r[5] = f2bf(b.y); r[6] = f2bf(b.z); r[7] = f2bf(b.w);
  *((u16x8*)out + i) = r;
}

// ---------------- GEMM-NT 128^2 (known-good; used for fused K/V proj) ---------
template <bool OUT_F32>
__global__ __launch_bounds__(256, 2)
void gemm_bt(const u16* __restrict__ A, const u16* __restrict__ Bw,
             void* __restrict__ C, int M, int N, int K) {
  __shared__ u16 lA[128 * 32];
  __shared__ u16 lB[128 * 32];
  const int tid = threadIdx.x;
  const int w = tid >> 6, l = tid & 63;
  const int lc = l & 15, lg = l >> 4;
  const int bn = blockIdx.x, bm = blockIdx.y;
  const int wr = w >> 1, wc = w & 1;
  const u16* Ab = A + (size_t)(bm * 128) * K;
  const u16* Bb = Bw + (size_t)(bn * 128) * K;
  const int srow = l >> 2;
  const int scol = (l & 3) * 8;

  f32x4 acc[4][4];
#pragma unroll
  for (int i = 0; i < 4; ++i)
#pragma unroll
    for (int j = 0; j < 4; ++j) acc[i][j] = (f32x4){0.f, 0.f, 0.f, 0.f};

  const int nk = K >> 5;
  for (int kt = 0; kt < nk; ++kt) {
    const int k0 = kt * 32;
    __syncthreads();
#pragma unroll
    for (int i = 0; i < 2; ++i) {
      const int rowA = (w * 2 + i) * 16;
      gl_lds16(Ab + (size_t)(rowA + srow) * K + k0 + scol, &lA[rowA * 32]);
      gl_lds16(Bb + (size_t)(rowA + srow) * K + k0 + scol, &lB[rowA * 32]);
    }
    __syncthreads();
    bf16x8 af[4], bfr[4];
#pragma unroll
    for (int mi = 0; mi < 4; ++mi)
      af[mi] = *(const bf16x8*)&lA[(wr * 64 + mi * 16 + lc) * 32 + lg * 8];
#pragma unroll
    for (int ni = 0; ni < 4; ++ni)
      bfr[ni] = *(const bf16x8*)&lB[(wc * 64 + ni * 16 + lc) * 32 + lg * 8];
#pragma unroll
    for (int mi = 0; mi < 4; ++mi)
#pragma unroll
      for (int ni = 0; ni < 4; ++ni)
        acc[mi][ni] = MFMA(af[mi], bfr[ni], acc[mi][ni]);
  }

#pragma unroll
  for (int mi = 0; mi < 4; ++mi)
#pragma unroll
    for (int ni = 0; ni < 4; ++ni)
#pragma unroll
      for (int r = 0; r < 4; ++r) {
        const int row = bm * 128 + wr * 64 + mi * 16 + lg * 4 + r;
        const int col = bn * 128 + wc * 64 + ni * 16 + lc;
        if constexpr (OUT_F32)
          ((float*)C)[(size_t)row * N + col] = acc[mi][ni][r];
        else
          ((u16*)C)[(size_t)row * N + col] = f2bf(acc[mi][ni][r]);
      }
}

// ---------------- GEMM-NT 256^2, BK=64, 8 waves, 4-phase pipelined ------------
// All 8 prefetch loads for tile t+1 issue at phase 0 (buffer cur^1 readers all
// done at t-1's final barrier) so the p3 vmcnt(0) waits on ~3.5-phase-old loads.
template <bool OUT_F32>
__global__ __launch_bounds__(512, 2)
void gemm256_bt(const u16* __restrict__ A, const u16* __restrict__ Bw,
                void* __restrict__ C, int M, int N, int K) {
  __shared__ u16 sA[2 * 256 * 64];
  __shared__ u16 sB[2 * 256 * 64];
  const int tid = threadIdx.x;
  const int w = tid >> 6, l = tid & 63;
  const int lc = l & 15, lg = l >> 4;
  const int wm = w >> 2, wn = w & 3;          // 2 x 4 wave grid
  const int nbn = N >> 8;
  const int nwg = (M >> 8) * nbn;
  const int cpx = nwg >> 3;
  const int lin = blockIdx.x;
  const int swz = (lin & 7) * cpx + (lin >> 3);
  const int bm = swz / nbn, bn = swz % nbn;
  const u16* Ab = A + (size_t)(bm * 256) * K;
  const u16* Bb = Bw + (size_t)(bn * 256) * K;
  const int lr = l >> 3;
  const int scc = ((l & 7) ^ lr) * 8;
  int cxg[2];
#pragma unroll
  for (int kk = 0; kk < 2; ++kk) cxg[kk] = ((kk * 4 + lg) ^ (lc & 7)) * 8;

  f32x4 acc[8][4];
#pragma unroll
  for (int i = 0; i < 8; ++i)
#pragma unroll
    for (int j = 0; j < 4; ++j) acc[i][j] = (f32x4){0.f, 0.f, 0.f, 0.f};

  auto STAGEA = [&](int buf, int t1, int h) {
    const int k0 = t1 * 64;
#pragma unroll
    for (int j = 0; j < 2; ++j) {
      const int r0 = h * 128 + w * 16 + j * 8;
      gl_lds16(Ab + (size_t)(r0 + lr) * K + k0 + scc, &sA[buf * 16384 + r0 * 64]);
    }
  };
  auto STAGEB = [&](int buf, int t1, int h) {
    const int k0 = t1 * 64;
#pragma unroll
    for (int j = 0; j < 2; ++j) {
      const int r0 = h * 128 + w * 16 + j * 8;
      gl_lds16(Bb + (size_t)(r0 + lr) * K + k0 + scc, &sB[buf * 16384 + r0 * 64]);
    }
  };

  STAGEA(0, 0, 0); STAGEA(0, 0, 1);
  STAGEB(0, 0, 0); STAGEB(0, 0, 1);
  asm volatile("s_waitcnt vmcnt(0)" ::: "memory");
  __builtin_amdgcn_s_barrier();
  asm volatile("" ::: "memory");

  const int nk = K >> 6;
  for (int t = 0; t < nk; ++t) {
    const int cur = t & 1;
    const int cb = cur * 16384;
    const bool pf = (t + 1 < nk);
#pragma unroll
    for (int p = 0; p < 4; ++p) {
      const int qm = p >> 1, qn = p & 1;
      bf16x8 af[4][2], bfr[2][2];
#pragma unroll
      for (int mi = 0; mi < 4; ++mi)
#pragma unroll
        for (int kk = 0; kk < 2; ++kk)
          af[mi][kk] = *(const bf16x8*)
              &sA[cb + (wm * 128 + qm * 64 + mi * 16 + lc) * 64 + cxg[kk]];
#pragma unroll
      for (int ni = 0; ni < 2; ++ni)
#pragma unroll
        for (int kk = 0; kk < 2; ++kk)
          bfr[ni][kk] = *(const bf16x8*)
              &sB[cb + (wn * 64 + qn * 32 + ni * 16 + lc) * 64 + cxg[kk]];
      if (pf && p == 0) {
        STAGEA(cur ^ 1, t + 1, 0); STAGEA(cur ^ 1, t + 1, 1);
        STAGEB(cur ^ 1, t + 1, 0); STAGEB(cur ^ 1, t + 1, 1);
      }
      __builtin_amdgcn_s_barrier();
      asm volatile("s_waitcnt lgkmcnt(0)" ::: "memory");
      __builtin_amdgcn_sched_barrier(0);
      __builtin_amdgcn_s_setprio(1);
#pragma unroll
      for (int kk = 0; kk < 2; ++kk)
#pragma unroll
        for (int mi = 0; mi < 4; ++mi)
#pragma unroll
          for (int ni = 0; ni < 2; ++ni)
            acc[qm * 4 + mi][qn * 2 + ni] =
                MFMA(af[mi][kk], bfr[ni][kk], acc[qm * 4 + mi][qn * 2 + ni]);
      __builtin_amdgcn_s_setprio(0);
      if (p == 3) asm volatile("s_waitcnt vmcnt(0)" ::: "memory");
      __builtin_amdgcn_s_barrier();
      asm volatile("" ::: "memory");
    }
  }

#pragma unroll
  for (int mi = 0; mi < 8; ++mi)
#pragma unroll
    for (int ni = 0; ni < 4; ++ni)
#pragma unroll
      for (int r = 0; r < 4; ++r) {
        const int row = bm * 256 + wm * 128 + mi * 16 + lg * 4 + r;
        const int col = bn * 256 + wn * 64 + ni * 16 + lc;
        if constexpr (OUT_F32)
          ((float*)C)[(size_t)row * N + col] = acc[mi][ni][r];
        else
          ((u16*)C)[(size_t)row * N + col] = f2bf(acc[mi][ni][r]);
      }
}

// ---------------- RoPE (row stride / col offset parametrized) ----------------
template <int NH, int STRIDE, int OFF>
__global__ void rope_kernel(const u16* __restrict__ lin, const float* __restrict__ fr,
                            u16* __restrict__ out, float scale) {
  int idx = blockIdx.x * 256 + threadIdx.x;
  const int total = B_ * S_ * NH * 64;
  if (idx >= total) return;
  const int i = idx & 63;
  const int h = (idx >> 6) % NH;
  const int t = idx / (64 * NH);
  const int s = t & (S_ - 1);
  const int b = t >> 11;
  const size_t src = (size_t)t * STRIDE + OFF + h * HD_ + 2 * i;
  const float x0 = bf2f(lin[src]);
  const float x1 = bf2f(lin[src + 1]);
  const float2 cs = ((const float2*)fr)[s * 64 + i];
  const float o0 = (x0 * cs.x - x1 * cs.y) * scale;
  const float o1 = (x1 * cs.x + x0 * cs.y) * scale;
  const size_t dst = ((size_t)((b * NH + h) * S_ + s)) * HD_ + 2 * i;
  out[dst] = f2bf(o0);
  out[dst + 1] = f2bf(o1);
}

// ---------------- V transpose (reads fused KV buffer, V at col offset 1024) ---
__global__ void vtrans_kernel(const u16* __restrict__ kvlin, u16* __restrict__ vt) {
  __shared__ u16 tile[32][33];
  const int tx = threadIdx.x, ty = threadIdx.y;  // (32, 8)
  const int s0 = blockIdx.x * 32;
  const int d0 = blockIdx.y * 32;
  const int bk = blockIdx.z;
  const int b = bk >> 3, kv = bk & 7;
#pragma unroll
  for (int r = 0; r < 4; ++r) {
    const int s = s0 + ty + r * 8;
    tile[ty + r * 8][tx] =
        kvlin[((size_t)(b * S_ + s)) * 2048 + 1024 + kv * HD_ + d0 + tx];
  }
  __syncthreads();
#pragma unroll
  for (int r = 0; r < 4; ++r) {
    const int d = d0 + ty + r * 8;
    vt[((size_t)bk * HD_ + d) * S_ + s0 + tx] = tile[tx][ty + r * 8];
  }
}

// ---------------- causal GQA flash attention (unchanged from round 8) ---------
__global__ __launch_bounds__(256, 2)
void attn_kernel(const u16* __restrict__ Q, const u16* __restrict__ K,
                 const u16* __restrict__ V, u16* __restrict__ O) {
  __shared__ u16 sK[2][64 * HD_];
  __shared__ u16 sV[2][HD_ * 64];
  const int tid = threadIdx.x;
  const int w = tid >> 6, l = tid & 63;
  const int hi = l >> 5, q32 = l & 31;
  const int kv = blockIdx.y, b = blockIdx.z;
  const int h = kv * 4 + w;
  const u16* Kp = K + ((size_t)(b * KVH_ + kv) * S_) * HD_;
  const u16* Vp = V + ((size_t)(b * KVH_ + kv) * HD_) * S_;

  int koff[4], voff[4];
#pragma unroll
  for (int i = 0; i < 4; ++i) {
    const int kr = w * 16 + i * 4 + (l >> 4);
    koff[i] = kr * HD_ + (((l & 15) ^ (kr & 7))) * 8;
    const int vr = w * 32 + i * 8 + (l >> 3);
    voff[i] = vr * S_ + (((l & 7) ^ (vr & 7))) * 8;
  }
  int cx[8];
#pragma unroll
  for (int c = 0; c < 8; ++c) cx[c] = ((c * 2 + hi) ^ (l & 7)) * 8;

  auto STAGE = [&](int bufi, int ti) {
    const u16* kg = Kp + (size_t)ti * (64 * HD_);
    const u16* vg = Vp + (size_t)ti * 64;
#pragma unroll
    for (int i = 0; i < 4; ++i) {
      gl_lds16(kg + koff[i], &sK[bufi][(w * 16 + i * 4) * HD_]);
      gl_lds16(vg + voff[i], &sV[bufi][(w * 32 + i * 8) * 64]);
    }
  };

  int cur = 0;
  for (int seg = 0; seg < 2; ++seg) {
    const int qt = seg ? (63 - blockIdx.x) : blockIdx.x;
    const int qg = qt * 32 + q32;
    const u16* Qp = Q + ((size_t)(b * H_ + h) * S_ + qt * 32) * HD_;

    bf16x8 qf[8];
#pragma unroll
    for (int ds = 0; ds < 8; ++ds)
      qf[ds] = *(const bf16x8*)(Qp + (size_t)q32 * HD_ + ds * 16 + hi * 8);
    asm volatile("s_waitcnt vmcnt(0)" ::: "memory");

    f32x16 out[4];
#pragma unroll
    for (int d = 0; d < 4; ++d)
#pragma unroll
      for (int r = 0; r < 16; ++r) out[d][r] = 0.f;
    float mrun = -1e30f, lrun = 0.f;

    const int nt = (qt >> 1) + 1;
    STAGE(cur, 0);

    for (int t = 0; t < nt; ++t) {
      if (t + 1 < nt) {
        STAGE(cur ^ 1, t + 1);
        asm volatile("s_waitcnt vmcnt(8)" ::: "memory");
      } else {
        asm volatile("s_waitcnt vmcnt(0)" ::: "memory");
      }
      __builtin_amdgcn_s_barrier();
      asm volatile("" ::: "memory");

      f32x16 sc0, sc1;
#pragma unroll
      for (int r = 0; r < 16; ++r) { sc0[r] = 0.f; sc1[r] = 0.f; }
      __builtin_amdgcn_s_setprio(1);
#pragma unroll
      for (int ds = 0; ds < 8; ++ds) {
        bf16x8 kf0 = *(const bf16x8*)&sK[cur][q32 * HD_ + cx[ds]];
        bf16x8 kf1 = *(const bf16x8*)&sK[cur][(32 + q32) * HD_ + cx[ds]];
        sc0 = MFMA32(kf0, qf[ds], sc0);
        sc1 = MFMA32(kf1, qf[ds], sc1);
      }
      __builtin_amdgcn_s_setprio(0);

      const bool diag = (t == nt - 1);
      float p0[16], p1[16];
#pragma unroll
      for (int r = 0; r < 16; ++r) {
        const int krow = (r & 3) + 8 * (r >> 2) + 4 * hi;
        float v0 = sc0[r], v1 = sc1[r];
        if (diag) {
          if (t * 64 + krow > qg) v0 = -1e9f;
          if (t * 64 + 32 + krow > qg) v1 = -1e9f;
        }
        p0[r] = v0; p1[r] = v1;
      }
      float rm = -1e30f;
#pragma unroll
      for (int r = 0; r < 16; ++r) rm = fmaxf(rm, fmaxf(p0[r], p1[r]));
      rm = fmaxf(rm, __shfl_xor(rm, 32, 64));
      if (!__all(rm <= mrun + 8.0f)) {
        const float mnew = fmaxf(mrun, rm);
        const float alpha = exp2v(mrun - mnew);
        mrun = mnew;
        lrun *= alpha;
#pragma unroll
        for (int d = 0; d < 4; ++d) out[d] *= alpha;
      }
      float sum = 0.f;
#pragma unroll
      for (int r = 0; r < 16; ++r) {
        p0[r] = exp2v(p0[r] - mrun);
        p1[r] = exp2v(p1[r] - mrun);
        sum += p0[r] + p1[r];
      }
      sum += __shfl_xor(sum, 32, 64);
      lrun += sum;
      uint32_t pk0[8], pk1[8];
#pragma unroll
      for (int g = 0; g < 4; ++g) {
        pk0[2 * g]     = cvtpk(p0[4 * g], p0[4 * g + 1]);
        pk0[2 * g + 1] = cvtpk(p0[4 * g + 2], p0[4 * g + 3]);
        pk1[2 * g]     = cvtpk(p1[4 * g], p1[4 * g + 1]);
        pk1[2 * g + 1] = cvtpk(p1[4 * g + 2], p1[4 * g + 3]);
      }
      PLSWAP(pk0[0], pk0[2]); PLSWAP(pk0[1], pk0[3]);
      PLSWAP(pk0[4], pk0[6]); PLSWAP(pk0[5], pk0[7]);
      PLSWAP(pk1[0], pk1[2]); PLSWAP(pk1[1], pk1[3]);
      PLSWAP(pk1[4], pk1[6]); PLSWAP(pk1[5], pk1[7]);
      bf16x8 pa[4];
      pa[0] = __builtin_bit_cast(bf16x8, (u32x4){pk0[0], pk0[1], pk0[2], pk0[3]});
      pa[1] = __builtin_bit_cast(bf16x8, (u32x4){pk0[4], pk0[5], pk0[6], pk0[7]});
      pa[2] = __builtin_bit_cast(bf16x8, (u32x4){pk1[0], pk1[1], pk1[2], pk1[3]});
      pa[3] = __builtin_bit_cast(bf16x8, (u32x4){pk1[4], pk1[5], pk1[6], pk1[7]});
      __builtin_amdgcn_s_setprio(1);
#pragma unroll
      for (int d = 0; d < 4; ++d) {
        const int vbase = (d * 32 + q32) * 64;
#pragma unroll
        for (int kk = 0; kk < 4; ++kk) {
          bf16x8 vf = *(const bf16x8*)&sV[cur][vbase + cx[kk]];
          out[d] = MFMA32(vf, pa[kk], out[d]);
        }
      }
      __builtin_amdgcn_s_setprio(0);
      asm volatile("" ::: "memory");
      __builtin_amdgcn_s_barrier();
      cur ^= 1;
    }

    const float inv = 1.0f / lrun;
    u16* myS = ((u16*)sK) + w * 4096;
#pragma unroll
    for (int d = 0; d < 4; ++d)
#pragma unroll
      for (int rq = 0; rq < 4; ++rq) {
        u32x2 pw;
        pw[0] = cvtpk(out[d][rq * 4 + 0] * inv, out[d][rq * 4 + 1] * inv);
        pw[1] = cvtpk(out[d][rq * 4 + 2] * inv, out[d][rq * 4 + 3] * inv);
        const int gin = (d * 8 + rq * 2 + hi) ^ (q32 & 15);
        *(u32x2*)&myS[q32 * 128 + gin * 4] = pw;
      }
    asm volatile("s_waitcnt lgkmcnt(0)" ::: "memory");
    __builtin_amdgcn_sched_barrier(0);
    const int rr = l >> 4;
    const int cc = l & 15;
#pragma unroll
    for (int p = 0; p < 8; ++p) {
      const int q = p * 4 + rr;
      const int ga = (2 * cc) ^ (q & 15);
      const int gb = (2 * cc + 1) ^ (q & 15);
      u32x2 va = *(const u32x2*)&myS[q * 128 + ga * 4];
      u32x2 vb = *(const u32x2*)&myS[q * 128 + gb * 4];
      u32x4 val = {va[0], va[1], vb[0], vb[1]};
      *(u32x4*)&O[((size_t)(b * S_ + qt * 32 + q)) * (H_ * HD_) + h * HD_ + cc * 8] = val;
    }
    if (seg == 0) {
      asm volatile("" ::: "memory");
      __builtin_amdgcn_s_barrier();
    }
  }
}

// ---------------- launch ----------------
extern "C" void kernel_launch(void* const* d_in, const int* in_sizes, int n_in,
                              void* d_out, int out_size, void* d_ws, size_t ws_size,
                              hipStream_t stream) {
  const float* x     = (const float*)d_in[0];
  const float* freqs = (const float*)d_in[2];
  const float* wq    = (const float*)d_in[4];
  const float* wk    = (const float*)d_in[5];
  const float* wv    = (const float*)d_in[6];
  const float* wo    = (const float*)d_in[7];

  char* ws = (char*)d_ws;
  u16* xb    = (u16*)(ws + 0);
  u16* wqb   = (u16*)(ws + 33554432);
  u16* wkb   = (u16*)(ws + 67108864);   // wkb+wvb = contiguous [2048][4096] bf16
  u16* wvb   = (u16*)(ws + 75497472);
  u16* qlin  = (u16*)(ws + 83886080);
  u16* kvlin = (u16*)(ws + 117440512);  // fused [4096][2048] bf16 (K cols 0-1023, V 1024-2047)
  u16* qr   = wqb;   // rope'd Q (pre-scaled by log2e/sqrt(128))
  u16* kr   = wkb;   // rope'd K
  u16* vt   = wvb;   // V^T
  u16* aout = qlin;  // attention output
  u16* wob  = xb;    // bf16 wo

  cast_kernel<<<8192, 256, 0, stream>>>(x, xb, 2097152);
  cast_kernel<<<8192, 256, 0, stream>>>(wq, wqb, 2097152);
  cast_kernel<<<2048, 256, 0, stream>>>(wk, wkb, 524288);
  cast_kernel<<<2048, 256, 0, stream>>>(wv, wvb, 524288);
  gemm256_bt<false><<<256, 512, 0, stream>>>(xb, wqb, qlin, 4096, 4096, 4096);
  gemm_bt<false><<<dim3(16, 32), 256, 0, stream>>>(xb, wkb, kvlin, 4096, 2048, 4096);
  rope_kernel<32, 4096, 0><<<32768, 256, 0, stream>>>(qlin, freqs, qr,
      0.08838834764831845f * 1.4426950408889634f);  // 1/sqrt(128) * log2(e)
  rope_kernel<8, 2048, 0><<<8192, 256, 0, stream>>>(kvlin, freqs, kr, 1.0f);
  vtrans_kernel<<<dim3(64, 4, 16), dim3(32, 8), 0, stream>>>(kvlin, vt);
  attn_kernel<<<dim3(32, 8, 2), 256, 0, stream>>>(qr, kr, vt, aout);
  cast_kernel<<<8192, 256, 0, stream>>>(wo, wob, 2097152);
  gemm256_bt<true><<<256, 512, 0, stream>>>(aout, wob, d_out, 4096, 4096, 4096);
}

// Round 10
// 527.081 us; speedup vs baseline: 1.8642x; 1.0863x over previous
//
#include <hip/hip_runtime.h>
#include <cstdint>
#include <cstddef>

#define B_   2
#define S_   2048
#define D_   4096
#define H_   32
#define KVH_ 8
#define HD_  128

typedef unsigned short u16;
typedef short     bf16x8 __attribute__((ext_vector_type(8)));
typedef float     f32x4  __attribute__((ext_vector_type(4)));
typedef float     f32x16 __attribute__((ext_vector_type(16)));
typedef u16       u16x8  __attribute__((ext_vector_type(8)));
typedef uint32_t  u32x2  __attribute__((ext_vector_type(2)));
typedef uint32_t  u32x4  __attribute__((ext_vector_type(4)));

__device__ __forceinline__ u16 f2bf(float f) {
  union { float f; uint32_t u; } v; v.f = f;
  uint32_t u = v.u;
  return (u16)((u + 0x7fffu + ((u >> 16) & 1u)) >> 16);
}
__device__ __forceinline__ float bf2f(u16 h) {
  union { uint32_t u; float f; } v; v.u = ((uint32_t)h) << 16;
  return v.f;
}
__device__ __forceinline__ uint32_t cvtpk(float lo, float hi_) {
  uint32_t r; asm("v_cvt_pk_bf16_f32 %0, %1, %2" : "=v"(r) : "v"(lo), "v"(hi_)); return r;
}
__device__ __forceinline__ float exp2v(float x) {
  float r; asm("v_exp_f32 %0, %1" : "=v"(r) : "v"(x)); return r;
}

__device__ __forceinline__ void gl_lds16(const void* g, void* l) {
  __builtin_amdgcn_global_load_lds(
      (const __attribute__((address_space(1))) void*)g,
      (__attribute__((address_space(3))) void*)l, 16, 0, 0);
}

#define MFMA(a, b, c)  __builtin_amdgcn_mfma_f32_16x16x32_bf16((a), (b), (c), 0, 0, 0)
#define MFMA32(a, b, c) __builtin_amdgcn_mfma_f32_32x32x16_bf16((a), (b), (c), 0, 0, 0)
#define PLSWAP(x, y) asm volatile("v_permlane32_swap_b32 %0, %1" : "+v"(x), "+v"(y))

// ---------------- cast f32 -> bf16 ----------------
__global__ void cast_kernel(const float* __restrict__ in, u16* __restrict__ out, int n8) {
  int i = blockIdx.x * blockDim.x + threadIdx.x;
  if (i >= n8) return;
  const float4* p = (const float4*)in + (size_t)i * 2;
  float4 a = p[0], b = p[1];
  u16x8 r;
  r[0] = f2bf(a.x); r[1] = f2bf(a.y); r[2] = f2bf(a.z); r[3] = f2bf(a.w);
  r[4] = f2bf(b.x); r[5] = f2bf(b.y); r[6] = f2bf(b.z); r[7] = f2bf(b.w);
  *((u16x8*)out + i) = r;
}

// ---------------- GEMM-NT 128^2 (known-good; used for fused K/V proj) ---------
template <bool OUT_F32>
__global__ __launch_bounds__(256, 2)
void gemm_bt(const u16* __restrict__ A, const u16* __restrict__ Bw,
             void* __restrict__ C, int M, int N, int K) {
  __shared__ u16 lA[128 * 32];
  __shared__ u16 lB[128 * 32];
  const int tid = threadIdx.x;
  const int w = tid >> 6, l = tid & 63;
  const int lc = l & 15, lg = l >> 4;
  const int bn = blockIdx.x, bm = blockIdx.y;
  const int wr = w >> 1, wc = w & 1;
  const u16* Ab = A + (size_t)(bm * 128) * K;
  const u16* Bb = Bw + (size_t)(bn * 128) * K;
  const int srow = l >> 2;
  const int scol = (l & 3) * 8;

  f32x4 acc[4][4];
#pragma unroll
  for (int i = 0; i < 4; ++i)
#pragma unroll
    for (int j = 0; j < 4; ++j) acc[i][j] = (f32x4){0.f, 0.f, 0.f, 0.f};

  const int nk = K >> 5;
  for (int kt = 0; kt < nk; ++kt) {
    const int k0 = kt * 32;
    __syncthreads();
#pragma unroll
    for (int i = 0; i < 2; ++i) {
      const int rowA = (w * 2 + i) * 16;
      gl_lds16(Ab + (size_t)(rowA + srow) * K + k0 + scol, &lA[rowA * 32]);
      gl_lds16(Bb + (size_t)(rowA + srow) * K + k0 + scol, &lB[rowA * 32]);
    }
    __syncthreads();
    bf16x8 af[4], bfr[4];
#pragma unroll
    for (int mi = 0; mi < 4; ++mi)
      af[mi] = *(const bf16x8*)&lA[(wr * 64 + mi * 16 + lc) * 32 + lg * 8];
#pragma unroll
    for (int ni = 0; ni < 4; ++ni)
      bfr[ni] = *(const bf16x8*)&lB[(wc * 64 + ni * 16 + lc) * 32 + lg * 8];
#pragma unroll
    for (int mi = 0; mi < 4; ++mi)
#pragma unroll
      for (int ni = 0; ni < 4; ++ni)
        acc[mi][ni] = MFMA(af[mi], bfr[ni], acc[mi][ni]);
  }

#pragma unroll
  for (int mi = 0; mi < 4; ++mi)
#pragma unroll
    for (int ni = 0; ni < 4; ++ni)
#pragma unroll
      for (int r = 0; r < 4; ++r) {
        const int row = bm * 128 + wr * 64 + mi * 16 + lg * 4 + r;
        const int col = bn * 128 + wc * 64 + ni * 16 + lc;
        if constexpr (OUT_F32)
          ((float*)C)[(size_t)row * N + col] = acc[mi][ni][r];
        else
          ((u16*)C)[(size_t)row * N + col] = f2bf(acc[mi][ni][r]);
      }
}

// ---------------- GEMM-NT 256^2, BK=64, 8 waves, half-tile pipelined ----------
// Phase p <-> (ha,hb): wave (wm,wn) computes rows ha*128+wm*64.., cols
// hb*128+wn*32.. so each phase reads exactly one A-half + one B-half.
// Steady staging: t+1:{B1,A1} @p0, t+2:A0 @p2, t+2:B0 @p3 (slots provably dead).
// Counted waits (never 0): p0 vmcnt(8), p1 vmcnt(10), p2 vmcnt(8), p3 none.
// ONE barrier per phase: barrier-at-top joins all waves after prior-phase
// lgkmcnt(0)+MFMA -> covers both read-after-DMA and DMA-overwrite-after-read.
template <bool OUT_F32>
__global__ __launch_bounds__(512, 2)
void gemm256_bt(const u16* __restrict__ A, const u16* __restrict__ Bw,
                void* __restrict__ C, int M, int N, int K) {
  __shared__ u16 sA[2 * 256 * 64];
  __shared__ u16 sB[2 * 256 * 64];
  const int tid = threadIdx.x;
  const int w = tid >> 6, l = tid & 63;
  const int lc = l & 15, lg = l >> 4;
  const int wm = w >> 2, wn = w & 3;          // 2 x 4 wave grid
  const int nbn = N >> 8;
  const int nwg = (M >> 8) * nbn;
  const int cpx = nwg >> 3;
  const int lin = blockIdx.x;
  const int swz = (lin & 7) * cpx + (lin >> 3);
  const int bm = swz / nbn, bn = swz % nbn;
  const u16* Ab = A + (size_t)(bm * 256) * K;
  const u16* Bb = Bw + (size_t)(bn * 256) * K;
  const int lr = l >> 3;
  const int scc = ((l & 7) ^ lr) * 8;
  int cxg[2];
#pragma unroll
  for (int kk = 0; kk < 2; ++kk) cxg[kk] = ((kk * 4 + lg) ^ (lc & 7)) * 8;

  f32x4 acc[8][4];
#pragma unroll
  for (int i = 0; i < 8; ++i)
#pragma unroll
    for (int j = 0; j < 4; ++j) acc[i][j] = (f32x4){0.f, 0.f, 0.f, 0.f};

  auto STAGEA = [&](int buf, int t1, int h) {
    const int k0 = t1 * 64;
#pragma unroll
    for (int j = 0; j < 2; ++j) {
      const int r0 = h * 128 + w * 16 + j * 8;
      gl_lds16(Ab + (size_t)(r0 + lr) * K + k0 + scc, &sA[buf * 16384 + r0 * 64]);
    }
  };
  auto STAGEB = [&](int buf, int t1, int h) {
    const int k0 = t1 * 64;
#pragma unroll
    for (int j = 0; j < 2; ++j) {
      const int r0 = h * 128 + w * 16 + j * 8;
      gl_lds16(Bb + (size_t)(r0 + lr) * K + k0 + scc, &sB[buf * 16384 + r0 * 64]);
    }
  };

  const int nk = K >> 6;
  // prologue mirrors steady-state issue order: A0,B0,B1,A1, 1:A0, 1:B0
  STAGEA(0, 0, 0); STAGEB(0, 0, 0);
  STAGEB(0, 0, 1); STAGEA(0, 0, 1);
  if (nk > 1) { STAGEA(1, 1, 0); STAGEB(1, 1, 0); }

  for (int t = 0; t < nk; ++t) {
    const int cur = t & 1;
    const int cb = cur * 16384;
    const int nb = (cur ^ 1);
#pragma unroll
    for (int p = 0; p < 4; ++p) {
      const int ha = p >> 1, hb = p & 1;
      // counted vmcnt: required half-tiles are the oldest outstanding loads
      if (p == 0)      asm volatile("s_waitcnt vmcnt(8)" ::: "memory");
      else if (p == 1) asm volatile("s_waitcnt vmcnt(10)" ::: "memory");
      else if (p == 2) asm volatile("s_waitcnt vmcnt(8)" ::: "memory");
      __builtin_amdgcn_s_barrier();
      asm volatile("" ::: "memory");
      // ds-read this phase's fragments (one A-half, one B-half)
      bf16x8 af[4][2], bfr[2][2];
#pragma unroll
      for (int mi = 0; mi < 4; ++mi)
#pragma unroll
        for (int kk = 0; kk < 2; ++kk)
          af[mi][kk] = *(const bf16x8*)
              &sA[cb + (ha * 128 + wm * 64 + mi * 16 + lc) * 64 + cxg[kk]];
#pragma unroll
      for (int ni = 0; ni < 2; ++ni)
#pragma unroll
        for (int kk = 0; kk < 2; ++kk)
          bfr[ni][kk] = *(const bf16x8*)
              &sB[cb + (hb * 128 + wn * 32 + ni * 16 + lc) * 64 + cxg[kk]];
      // stage issues into provably-dead slots
      if (p == 0 && t + 1 < nk) { STAGEB(nb, t + 1, 1); STAGEA(nb, t + 1, 1); }
      if (p == 2 && t + 2 < nk) { STAGEA(cur, t + 2, 0); }
      if (p == 3 && t + 2 < nk) { STAGEB(cur, t + 2, 0); }
      asm volatile("s_waitcnt lgkmcnt(0)" ::: "memory");
      __builtin_amdgcn_sched_barrier(0);
      __builtin_amdgcn_s_setprio(1);
#pragma unroll
      for (int kk = 0; kk < 2; ++kk)
#pragma unroll
        for (int mi = 0; mi < 4; ++mi)
#pragma unroll
          for (int ni = 0; ni < 2; ++ni)
            acc[ha * 4 + mi][hb * 2 + ni] =
                MFMA(af[mi][kk], bfr[ni][kk], acc[ha * 4 + mi][hb * 2 + ni]);
      __builtin_amdgcn_s_setprio(0);
    }
  }

#pragma unroll
  for (int ha = 0; ha < 2; ++ha)
#pragma unroll
    for (int mi = 0; mi < 4; ++mi)
#pragma unroll
      for (int hb = 0; hb < 2; ++hb)
#pragma unroll
        for (int ni = 0; ni < 2; ++ni)
#pragma unroll
          for (int r = 0; r < 4; ++r) {
            const int row = bm * 256 + ha * 128 + wm * 64 + mi * 16 + lg * 4 + r;
            const int col = bn * 256 + hb * 128 + wn * 32 + ni * 16 + lc;
            if constexpr (OUT_F32)
              ((float*)C)[(size_t)row * N + col] = acc[ha * 4 + mi][hb * 2 + ni][r];
            else
              ((u16*)C)[(size_t)row * N + col] = f2bf(acc[ha * 4 + mi][hb * 2 + ni][r]);
          }
}

// ---------------- RoPE (row stride / col offset parametrized) ----------------
template <int NH, int STRIDE, int OFF>
__global__ void rope_kernel(const u16* __restrict__ lin, const float* __restrict__ fr,
                            u16* __restrict__ out, float scale) {
  int idx = blockIdx.x * 256 + threadIdx.x;
  const int total = B_ * S_ * NH * 64;
  if (idx >= total) return;
  const int i = idx & 63;
  const int h = (idx >> 6) % NH;
  const int t = idx / (64 * NH);
  const int s = t & (S_ - 1);
  const int b = t >> 11;
  const size_t src = (size_t)t * STRIDE + OFF + h * HD_ + 2 * i;
  const float x0 = bf2f(lin[src]);
  const float x1 = bf2f(lin[src + 1]);
  const float2 cs = ((const float2*)fr)[s * 64 + i];
  const float o0 = (x0 * cs.x - x1 * cs.y) * scale;
  const float o1 = (x1 * cs.x + x0 * cs.y) * scale;
  const size_t dst = ((size_t)((b * NH + h) * S_ + s)) * HD_ + 2 * i;
  out[dst] = f2bf(o0);
  out[dst + 1] = f2bf(o1);
}

// ---------------- V transpose (reads fused KV buffer, V at col offset 1024) ---
__global__ void vtrans_kernel(const u16* __restrict__ kvlin, u16* __restrict__ vt) {
  __shared__ u16 tile[32][33];
  const int tx = threadIdx.x, ty = threadIdx.y;  // (32, 8)
  const int s0 = blockIdx.x * 32;
  const int d0 = blockIdx.y * 32;
  const int bk = blockIdx.z;
  const int b = bk >> 3, kv = bk & 7;
#pragma unroll
  for (int r = 0; r < 4; ++r) {
    const int s = s0 + ty + r * 8;
    tile[ty + r * 8][tx] =
        kvlin[((size_t)(b * S_ + s)) * 2048 + 1024 + kv * HD_ + d0 + tx];
  }
  __syncthreads();
#pragma unroll
  for (int r = 0; r < 4; ++r) {
    const int d = d0 + ty + r * 8;
    vt[((size_t)bk * HD_ + d) * S_ + s0 + tx] = tile[tx][ty + r * 8];
  }
}

// ---------------- causal GQA flash attention (unchanged from round 8) ---------
__global__ __launch_bounds__(256, 2)
void attn_kernel(const u16* __restrict__ Q, const u16* __restrict__ K,
                 const u16* __restrict__ V, u16* __restrict__ O) {
  __shared__ u16 sK[2][64 * HD_];
  __shared__ u16 sV[2][HD_ * 64];
  const int tid = threadIdx.x;
  const int w = tid >> 6, l = tid & 63;
  const int hi = l >> 5, q32 = l & 31;
  const int kv = blockIdx.y, b = blockIdx.z;
  const int h = kv * 4 + w;
  const u16* Kp = K + ((size_t)(b * KVH_ + kv) * S_) * HD_;
  const u16* Vp = V + ((size_t)(b * KVH_ + kv) * HD_) * S_;

  int koff[4], voff[4];
#pragma unroll
  for (int i = 0; i < 4; ++i) {
    const int kr = w * 16 + i * 4 + (l >> 4);
    koff[i] = kr * HD_ + (((l & 15) ^ (kr & 7))) * 8;
    const int vr = w * 32 + i * 8 + (l >> 3);
    voff[i] = vr * S_ + (((l & 7) ^ (vr & 7))) * 8;
  }
  int cx[8];
#pragma unroll
  for (int c = 0; c < 8; ++c) cx[c] = ((c * 2 + hi) ^ (l & 7)) * 8;

  auto STAGE = [&](int bufi, int ti) {
    const u16* kg = Kp + (size_t)ti * (64 * HD_);
    const u16* vg = Vp + (size_t)ti * 64;
#pragma unroll
    for (int i = 0; i < 4; ++i) {
      gl_lds16(kg + koff[i], &sK[bufi][(w * 16 + i * 4) * HD_]);
      gl_lds16(vg + voff[i], &sV[bufi][(w * 32 + i * 8) * 64]);
    }
  };

  int cur = 0;
  for (int seg = 0; seg < 2; ++seg) {
    const int qt = seg ? (63 - blockIdx.x) : blockIdx.x;
    const int qg = qt * 32 + q32;
    const u16* Qp = Q + ((size_t)(b * H_ + h) * S_ + qt * 32) * HD_;

    bf16x8 qf[8];
#pragma unroll
    for (int ds = 0; ds < 8; ++ds)
      qf[ds] = *(const bf16x8*)(Qp + (size_t)q32 * HD_ + ds * 16 + hi * 8);
    asm volatile("s_waitcnt vmcnt(0)" ::: "memory");

    f32x16 out[4];
#pragma unroll
    for (int d = 0; d < 4; ++d)
#pragma unroll
      for (int r = 0; r < 16; ++r) out[d][r] = 0.f;
    float mrun = -1e30f, lrun = 0.f;

    const int nt = (qt >> 1) + 1;
    STAGE(cur, 0);

    for (int t = 0; t < nt; ++t) {
      if (t + 1 < nt) {
        STAGE(cur ^ 1, t + 1);
        asm volatile("s_waitcnt vmcnt(8)" ::: "memory");
      } else {
        asm volatile("s_waitcnt vmcnt(0)" ::: "memory");
      }
      __builtin_amdgcn_s_barrier();
      asm volatile("" ::: "memory");

      f32x16 sc0, sc1;
#pragma unroll
      for (int r = 0; r < 16; ++r) { sc0[r] = 0.f; sc1[r] = 0.f; }
      __builtin_amdgcn_s_setprio(1);
#pragma unroll
      for (int ds = 0; ds < 8; ++ds) {
        bf16x8 kf0 = *(const bf16x8*)&sK[cur][q32 * HD_ + cx[ds]];
        bf16x8 kf1 = *(const bf16x8*)&sK[cur][(32 + q32) * HD_ + cx[ds]];
        sc0 = MFMA32(kf0, qf[ds], sc0);
        sc1 = MFMA32(kf1, qf[ds], sc1);
      }
      __builtin_amdgcn_s_setprio(0);

      const bool diag = (t == nt - 1);
      float p0[16], p1[16];
#pragma unroll
      for (int r = 0; r < 16; ++r) {
        const int krow = (r & 3) + 8 * (r >> 2) + 4 * hi;
        float v0 = sc0[r], v1 = sc1[r];
        if (diag) {
          if (t * 64 + krow > qg) v0 = -1e9f;
          if (t * 64 + 32 + krow > qg) v1 = -1e9f;
        }
        p0[r] = v0; p1[r] = v1;
      }
      float rm = -1e30f;
#pragma unroll
      for (int r = 0; r < 16; ++r) rm = fmaxf(rm, fmaxf(p0[r], p1[r]));
      rm = fmaxf(rm, __shfl_xor(rm, 32, 64));
      if (!__all(rm <= mrun + 8.0f)) {
        const float mnew = fmaxf(mrun, rm);
        const float alpha = exp2v(mrun - mnew);
        mrun = mnew;
        lrun *= alpha;
#pragma unroll
        for (int d = 0; d < 4; ++d) out[d] *= alpha;
      }
      float sum = 0.f;
#pragma unroll
      for (int r = 0; r < 16; ++r) {
        p0[r] = exp2v(p0[r] - mrun);
        p1[r] = exp2v(p1[r] - mrun);
        sum += p0[r] + p1[r];
      }
      sum += __shfl_xor(sum, 32, 64);
      lrun += sum;
      uint32_t pk0[8], pk1[8];
#pragma unroll
      for (int g = 0; g < 4; ++g) {
        pk0[2 * g]     = cvtpk(p0[4 * g], p0[4 * g + 1]);
        pk0[2 * g + 1] = cvtpk(p0[4 * g + 2], p0[4 * g + 3]);
        pk1[2 * g]     = cvtpk(p1[4 * g], p1[4 * g + 1]);
        pk1[2 * g + 1] = cvtpk(p1[4 * g + 2], p1[4 * g + 3]);
      }
      PLSWAP(pk0[0], pk0[2]); PLSWAP(pk0[1], pk0[3]);
      PLSWAP(pk0[4], pk0[6]); PLSWAP(pk0[5], pk0[7]);
      PLSWAP(pk1[0], pk1[2]); PLSWAP(pk1[1], pk1[3]);
      PLSWAP(pk1[4], pk1[6]); PLSWAP(pk1[5], pk1[7]);
      bf16x8 pa[4];
      pa[0] = __builtin_bit_cast(bf16x8, (u32x4){pk0[0], pk0[1], pk0[2], pk0[3]});
      pa[1] = __builtin_bit_cast(bf16x8, (u32x4){pk0[4], pk0[5], pk0[6], pk0[7]});
      pa[2] = __builtin_bit_cast(bf16x8, (u32x4){pk1[0], pk1[1], pk1[2], pk1[3]});
      pa[3] = __builtin_bit_cast(bf16x8, (u32x4){pk1[4], pk1[5], pk1[6], pk1[7]});
      __builtin_amdgcn_s_setprio(1);
#pragma unroll
      for (int d = 0; d < 4; ++d) {
        const int vbase = (d * 32 + q32) * 64;
#pragma unroll
        for (int kk = 0; kk < 4; ++kk) {
          bf16x8 vf = *(const bf16x8*)&sV[cur][vbase + cx[kk]];
          out[d] = MFMA32(vf, pa[kk], out[d]);
        }
      }
      __builtin_amdgcn_s_setprio(0);
      asm volatile("" ::: "memory");
      __builtin_amdgcn_s_barrier();
      cur ^= 1;
    }

    const float inv = 1.0f / lrun;
    u16* myS = ((u16*)sK) + w * 4096;
#pragma unroll
    for (int d = 0; d < 4; ++d)
#pragma unroll
      for (int rq = 0; rq < 4; ++rq) {
        u32x2 pw;
        pw[0] = cvtpk(out[d][rq * 4 + 0] * inv, out[d][rq * 4 + 1] * inv);
        pw[1] = cvtpk(out[d][rq * 4 + 2] * inv, out[d][rq * 4 + 3] * inv);
        const int gin = (d * 8 + rq * 2 + hi) ^ (q32 & 15);
        *(u32x2*)&myS[q32 * 128 + gin * 4] = pw;
      }
    asm volatile("s_waitcnt lgkmcnt(0)" ::: "memory");
    __builtin_amdgcn_sched_barrier(0);
    const int rr = l >> 4;
    const int cc = l & 15;
#pragma unroll
    for (int p = 0; p < 8; ++p) {
      const int q = p * 4 + rr;
      const int ga = (2 * cc) ^ (q & 15);
      const int gb = (2 * cc + 1) ^ (q & 15);
      u32x2 va = *(const u32x2*)&myS[q * 128 + ga * 4];
      u32x2 vb = *(const u32x2*)&myS[q * 128 + gb * 4];
      u32x4 val = {va[0], va[1], vb[0], vb[1]};
      *(u32x4*)&O[((size_t)(b * S_ + qt * 32 + q)) * (H_ * HD_) + h * HD_ + cc * 8] = val;
    }
    if (seg == 0) {
      asm volatile("" ::: "memory");
      __builtin_amdgcn_s_barrier();
    }
  }
}

// ---------------- launch ----------------
extern "C" void kernel_launch(void* const* d_in, const int* in_sizes, int n_in,
                              void* d_out, int out_size, void* d_ws, size_t ws_size,
                              hipStream_t stream) {
  const float* x     = (const float*)d_in[0];
  const float* freqs = (const float*)d_in[2];
  const float* wq    = (const float*)d_in[4];
  const float* wk    = (const float*)d_in[5];
  const float* wv    = (const float*)d_in[6];
  const float* wo    = (const float*)d_in[7];

  char* ws = (char*)d_ws;
  u16* xb    = (u16*)(ws + 0);
  u16* wqb   = (u16*)(ws + 33554432);
  u16* wkb   = (u16*)(ws + 67108864);   // wkb+wvb = contiguous [2048][4096] bf16
  u16* wvb   = (u16*)(ws + 75497472);
  u16* qlin  = (u16*)(ws + 83886080);
  u16* kvlin = (u16*)(ws + 117440512);  // fused [4096][2048] bf16
  u16* qr   = wqb;   // rope'd Q (pre-scaled by log2e/sqrt(128))
  u16* kr   = wkb;   // rope'd K
  u16* vt   = wvb;   // V^T
  u16* aout = qlin;  // attention output
  u16* wob  = xb;    // bf16 wo

  cast_kernel<<<8192, 256, 0, stream>>>(x, xb, 2097152);
  cast_kernel<<<8192, 256, 0, stream>>>(wq, wqb, 2097152);
  cast_kernel<<<2048, 256, 0, stream>>>(wk, wkb, 524288);
  cast_kernel<<<2048, 256, 0, stream>>>(wv, wvb, 524288);
  gemm256_bt<false><<<256, 512, 0, stream>>>(xb, wqb, qlin, 4096, 4096, 4096);
  gemm_bt<false><<<dim3(16, 32), 256, 0, stream>>>(xb, wkb, kvlin, 4096, 2048, 4096);
  rope_kernel<32, 4096, 0><<<32768, 256, 0, stream>>>(qlin, freqs, qr,
      0.08838834764831845f * 1.4426950408889634f);  // 1/sqrt(128) * log2(e)
  rope_kernel<8, 2048, 0><<<8192, 256, 0, stream>>>(kvlin, freqs, kr, 1.0f);
  vtrans_kernel<<<dim3(64, 4, 16), dim3(32, 8), 0, stream>>>(kvlin, vt);
  attn_kernel<<<dim3(32, 8, 2), 256, 0, stream>>>(qr, kr, vt, aout);
  cast_kernel<<<8192, 256, 0, stream>>>(wo, wob, 2097152);
  gemm256_bt<true><<<256, 512, 0, stream>>>(aout, wob, d_out, 4096, 4096, 4096);
}